// Round 7
// baseline (523.682 us; speedup 1.0000x reference)
//
#include <hip/hip_runtime.h>
#include <cstdint>

typedef unsigned short u16;
typedef unsigned int u32;
typedef unsigned char u8;
typedef unsigned long long u64;
typedef __attribute__((ext_vector_type(8))) short short8;
typedef __attribute__((ext_vector_type(4))) float f32x4;

#define CAP 131072  // max compact slots at 128^3 (~105k expected active)

__device__ __forceinline__ float bf1(u16 v){ union{u32 i; float f;} c; c.i = ((u32)v) << 16; return c.f; }
__device__ __forceinline__ u16 f2bf(float f){
    union{float f; u32 i;} c; c.f = f; u32 i = c.i;
    return (u16)((i + 0x7FFFu + ((i >> 16) & 1u)) >> 16);   // RTNE
}
__device__ __forceinline__ u16 bits2bf(u32 b){ union{u32 i; float f;} c; c.i = b; return f2bf(c.f); }

struct PAll {
    const void* w[9];
    u32 wstart[10];
    int cin[9], cout[9], mode[9];   // 0=16x16 wfrag, 1=d0 pair(16->32), 2=subm0 pair(16->16)
    const void* s[18];
};

// ---- fused phase 0+1: blocks [0,8192) = active bitmask + packed features;
// blocks [8192,..) = weight-fragment + scale prep. Flag self-derived per thread. ----
__global__ __launch_bounds__(256)
void prepact_k(PAll J, u16* __restrict__ FR, float* __restrict__ S,
               const u16* __restrict__ s0a_probe, u32* __restrict__ flag,
               const void* __restrict__ xv, u64* __restrict__ bmask,
               u32* __restrict__ cnt, u16* __restrict__ Xp){
    int ok = 1;
    #pragma unroll
    for (int i = 0; i < 8; i += 2){
        u16 vv = s0a_probe[i];
        if (vv < 0x3F00u || vv > 0x3FC0u) ok = 0;
    }
    const u32 isbf = ok ? 1u : 0u;

    if (blockIdx.x < 8192){
        const int v = blockIdx.x * 256 + threadIdx.x;
        const size_t N = 2097152;
        u16 vals[16];
        u32 a = 0;
        if (isbf) {
            const u16* x = (const u16*)xv;
            #pragma unroll
            for (int c = 0; c < 16; ++c){
                const u16 b = x[(size_t)c * N + v];
                vals[c] = b;
                a |= (u32)b & 0x7FFFu;
            }
        } else {
            const u32* x = (const u32*)xv;
            #pragma unroll
            for (int c = 0; c < 16; ++c){
                const u32 b = x[(size_t)c * N + v];
                vals[c] = bits2bf(b);
                a |= b & 0x7FFFFFFFu;
            }
        }
        const bool act = (a != 0);
        const u64 m = __ballot(act);
        __shared__ u32 wc[4];
        const int lane = threadIdx.x & 63, wv = threadIdx.x >> 6;
        if (lane == 0) { bmask[v >> 6] = m; wc[wv] = (u32)__popcll(m); }
        __syncthreads();
        if (act){
            u32 wbase = 0;
            for (int i = 0; i < wv; ++i) wbase += wc[i];
            const u32 local = wbase + (u32)__popcll(m & ((1ull << lane) - 1ull));
            u16* dst = Xp + ((size_t)blockIdx.x * 256 + local) * 16;
            *(short8*)(dst)     = *(const short8*)(vals);
            *(short8*)(dst + 8) = *(const short8*)(vals + 8);
        }
        return;
    }

    const int gi = (int)(blockIdx.x - 8192) * 256 + threadIdx.x;
    if (gi == 0) { flag[0] = isbf; cnt[0] = 0; }

    const int wtot = (int)J.wstart[9];
    if (gi < wtot){
        int j = 0;
        while (gi >= (int)J.wstart[j + 1]) ++j;
        const int i = gi - (int)J.wstart[j];
        const void* w = J.w[j];
        const int CIN = J.cin[j], COUT = J.cout[j];
        const int jj = i & 7;
        const int lane = (i >> 3) & 63;
        int rest = i >> 9;
        int src = -1;
        if (J.mode[j] == 0){
            const int KC = CIN >> 5, NT = COUT >> 4;
            const int nt = rest % NT; rest /= NT;
            const int kc = rest % KC; const int tap = rest / KC;
            const int k = kc * 32 + (lane >> 4) * 8 + jj;
            const int co = nt * 16 + (lane & 15);
            src = (tap * CIN + k) * COUT + co;
        } else if (J.mode[j] == 1){
            const int nt = rest & 1; const int pair = rest >> 1;
            const int kg = (lane >> 4) * 8 + jj;
            const int tap = pair * 2 + (kg >> 4);
            const int ci = kg & 15;
            const int co = nt * 16 + (lane & 15);
            if (tap < 27) src = (tap * 16 + ci) * 32 + co;
        } else {
            const int pair = rest;
            const int kg = (lane >> 4) * 8 + jj;
            const int tap = pair * 2 + (kg >> 4);
            const int ci = kg & 15;
            const int co = lane & 15;
            if (tap < 27) src = (tap * 16 + ci) * 16 + co;
        }
        float v = 0.f;
        if (src >= 0) v = isbf ? bf1(((const u16*)w)[src]) : ((const float*)w)[src];
        FR[gi] = f2bf(v);
    } else {
        const int i2 = gi - wtot;
        const int len[18] = {16,16,16,16,32,32,32,32,32,32,64,64,64,64,64,64,64,64};
        const int off[18] = {0,16,32,48,64,96,128,160,192,224,256,320,384,448,512,576,640,704};
        if (i2 < 768){
            int b = 0, base = 0;
            while (i2 >= base + len[b]) { base += len[b]; ++b; }
            const int t = i2 - base;
            const float v = isbf ? bf1(((const u16*)J.s[b])[t]) : ((const float*)J.s[b])[t];
            S[off[b] + t] = v;
        }
    }
}

// ---- fused: scatter (16 tiles/block, ONE atomic per block) + m1 + m2 from bmask ----
// blocks [0,512): scatter; [512,1536): m1; [1536,1664): m2
__global__ __launch_bounds__(256)
void scatter2m_k(const u16* __restrict__ Xp, const u64* __restrict__ bmask,
                 int* __restrict__ idxmap, int* __restrict__ alist,
                 u16* __restrict__ f, u32* __restrict__ cnt,
                 u8* __restrict__ m1, u8* __restrict__ m2){
    if (blockIdx.x < 512){
        const int lane = threadIdx.x & 63, wv = threadIdx.x >> 6;
        __shared__ u32 wcnt[16][4];
        __shared__ u32 tileoff[16];
        __shared__ u32 sbase;
        const int tile0 = blockIdx.x * 16;

        #pragma unroll
        for (int i = 0; i < 16; ++i){
            if (lane == 0){
                const u64 m = bmask[(size_t)(tile0 + i) * 4 + wv];
                wcnt[i][wv] = (u32)__popcll(m);
            }
        }
        __syncthreads();
        if (threadIdx.x == 0){
            u32 s = 0;
            #pragma unroll
            for (int i = 0; i < 16; ++i){
                tileoff[i] = s;
                s += wcnt[i][0] + wcnt[i][1] + wcnt[i][2] + wcnt[i][3];
            }
            sbase = atomicAdd(cnt, s);
        }
        __syncthreads();
        const u32 b0 = sbase;
        #pragma unroll
        for (int i = 0; i < 16; ++i){
            const u64 m = bmask[(size_t)(tile0 + i) * 4 + wv];
            const bool act = (m >> lane) & 1ull;
            u32 wbase = 0;
            for (int k = 0; k < wv; ++k) wbase += wcnt[i][k];
            const u32 rank = (u32)__popcll(m & ((1ull << lane) - 1ull));
            const int v = (tile0 + i) * 256 + threadIdx.x;
            int slot = -1;
            if (act){
                const u32 sl = b0 + tileoff[i] + wbase + rank;
                if (sl < CAP){
                    slot = (int)sl;
                    alist[slot] = v;
                    const u16* src = Xp + ((size_t)(tile0 + i) * 256 + wbase + rank) * 16;
                    u16* dst = f + (size_t)slot * 16;
                    *(short8*)(dst)     = *(const short8*)(src);
                    *(short8*)(dst + 8) = *(const short8*)(src + 8);
                }
            }
            idxmap[v] = slot;
        }
    } else if (blockIdx.x < 1536){
        const int v = (int)(blockIdx.x - 512) * 256 + threadIdx.x;
        const int xo = v & 63, yo = (v >> 6) & 63, zo = v >> 12;
        u32 a = 0;
        #pragma unroll
        for (int kz = 0; kz < 3; ++kz){ const int iz = 2*zo + kz - 1; if ((unsigned)iz >= 128u) continue;
          #pragma unroll
          for (int ky = 0; ky < 3; ++ky){ const int iy = 2*yo + ky - 1; if ((unsigned)iy >= 128u) continue;
            #pragma unroll
            for (int kx = 0; kx < 3; ++kx){ const int ix = 2*xo + kx - 1; if ((unsigned)ix >= 128u) continue;
              const int vv = (iz * 128 + iy) * 128 + ix;
              a |= (u32)((bmask[vv >> 6] >> (vv & 63)) & 1ull);
        }}}
        m1[v] = (u8)a;
    } else {
        const int v = (int)(blockIdx.x - 1536) * 256 + threadIdx.x;
        const int xo = v & 31, yo = (v >> 5) & 31, zo = v >> 10;
        const int xlo = max(0, 4*xo - 3), xhi = min(127, 4*xo + 3);
        const int w0 = xlo >> 6, w1 = xhi >> 6;
        u32 a = 0;
        #pragma unroll
        for (int dz = -3; dz <= 3; ++dz){ const int iz = 4*zo + dz; if ((unsigned)iz >= 128u) continue;
          #pragma unroll
          for (int dy = -3; dy <= 3; ++dy){ const int iy = 4*yo + dy; if ((unsigned)iy >= 128u) continue;
            const int rowword = ((iz * 128 + iy) * 128) >> 6;
            if (w0 == w1){
                const u64 mw = bmask[rowword + w0];
                const int sh = xlo & 63, len = xhi - xlo + 1;
                if ((mw >> sh) & ((1ull << len) - 1ull)) a = 1;
            } else {
                const u64 lo = bmask[rowword + w0] >> (xlo & 63);
                const u64 hi = bmask[rowword + w1] & ((1ull << ((xhi & 63) + 1)) - 1ull);
                if (lo | hi) a = 1;
            }
        }}
        m2[v] = (u8)a;
    }
}

// ---- MFMA sparse subm conv at 128^3: compact bf16 16ch -> 16ch ----
// MEASUREMENT: block-index fold (bx & 2047) — grid may be doubled; duplicate half
// recomputes identical outputs (benign identical-value write race).
__global__ __launch_bounds__(256)
void sconvm_k(const u16* __restrict__ fin, const int* __restrict__ idxmap,
              const int* __restrict__ alist, const u32* __restrict__ cnt,
              const u16* __restrict__ wf, const float* __restrict__ sc,
              const float* __restrict__ sh, u16* __restrict__ fout){
    const int n = min((int)cnt[0], CAP);
    const int bx = (int)(blockIdx.x & 2047u);
    const int j = bx * 4 + (threadIdx.x >> 6);
    const int sbase = j * 16;
    if (sbase >= n) return;
    const int lane = threadIdx.x & 63;
    const int m = lane & 15, quad = lane >> 4;

    const int s = sbase + m;
    const int v = (s < n) ? alist[s] : -1;
    int xo = 0, yo = 0, zo = 0;
    if (v >= 0){ xo = v & 127; yo = (v >> 7) & 127; zo = v >> 14; }

    int sn[14];
    #pragma unroll
    for (int p = 0; p < 14; ++p){
        const int tp = p * 2 + (quad >> 1);
        int sv = -1;
        if (v >= 0 && tp < 27){
            const int kz = tp / 9, ky = (tp / 3) % 3, kx = tp % 3;
            const int iz = zo + kz - 1, iy = yo + ky - 1, ix = xo + kx - 1;
            if ((unsigned)iz < 128u && (unsigned)iy < 128u && (unsigned)ix < 128u){
                sv = idxmap[((size_t)iz * 128 + iy) * 128 + ix];
            }
        }
        sn[p] = sv;
    }

    f32x4 acc = {0.f,0.f,0.f,0.f};
    #pragma unroll
    for (int p = 0; p < 14; ++p){
        short8 a = {0,0,0,0,0,0,0,0};
        if (sn[p] >= 0) a = *(const short8*)(fin + (size_t)sn[p] * 16 + (quad & 1) * 8);
        short8 b = *(const short8*)(wf + ((size_t)p * 64 + lane) * 8);
        acc = __builtin_amdgcn_mfma_f32_16x16x32_bf16(a, b, acc, 0, 0, 0);
    }

    const int co = lane & 15;
    const float scl = sc[co], shf = sh[co];
    #pragma unroll
    for (int r = 0; r < 4; ++r){
        const int srow = sbase + quad * 4 + r;
        if (srow < n){
            fout[(size_t)srow * 16 + co] = f2bf(fmaxf(acc[r] * scl + shf, 0.f));
        }
    }
}

// ---- down0 MFMA: compact bf16 16ch @128^3 -> bf16 NDHWC 32ch @64^3 ----
// MEASUREMENT: fold at 4096 (grid may be 8192).
__global__ __launch_bounds__(256)
void convd0m_k(const u16* __restrict__ fbuf, const int* __restrict__ idxmap,
               const u16* __restrict__ wf, const float* __restrict__ sc,
               const float* __restrict__ sh, const u8* __restrict__ mk,
               u16* __restrict__ out)
{
    const int bx = (int)(blockIdx.x & 4095u);
    const int wj = bx * 4 + (threadIdx.x >> 6);
    const int lane = threadIdx.x & 63;
    const int m = lane & 15, quad = lane >> 4;
    const int xo_b = (wj & 3) * 16;
    const int yo = (wj >> 2) & 63;
    const int zo = wj >> 8;
    const int ix_m = (xo_b + m) * 2 - 1;

    int sn[14];
    #pragma unroll
    for (int p = 0; p < 14; ++p){
        const int tp = p * 2 + (quad >> 1);
        int sv = -1;
        if (tp < 27){
            const int kz = tp / 9, ky = (tp / 3) % 3, kx = tp % 3;
            const int iz = 2*zo + kz - 1, iy = 2*yo + ky - 1, ix = ix_m + kx;
            if ((unsigned)iz < 128u && (unsigned)iy < 128u && (unsigned)ix < 128u){
                sv = idxmap[((size_t)iz * 128 + iy) * 128 + ix];
            }
        }
        sn[p] = sv;
    }

    f32x4 acc0 = {0.f,0.f,0.f,0.f}, acc1 = {0.f,0.f,0.f,0.f};
    #pragma unroll
    for (int p = 0; p < 14; ++p){
        short8 a = {0,0,0,0,0,0,0,0};
        if (sn[p] >= 0) a = *(const short8*)(fbuf + (size_t)sn[p] * 16 + (quad & 1) * 8);
        short8 b0 = *(const short8*)(wf + ((size_t)(p*2+0) * 64 + lane) * 8);
        short8 b1 = *(const short8*)(wf + ((size_t)(p*2+1) * 64 + lane) * 8);
        acc0 = __builtin_amdgcn_mfma_f32_16x16x32_bf16(a, b0, acc0, 0, 0, 0);
        acc1 = __builtin_amdgcn_mfma_f32_16x16x32_bf16(a, b1, acc1, 0, 0, 0);
    }

    const int vb = wj * 16 + quad * 4;
    const u32 m4 = *(const u32*)(mk + vb);
    const int n = lane & 15;
    #pragma unroll
    for (int nt = 0; nt < 2; ++nt){
        const int co = nt * 16 + n;
        const float s = sc[co], h = sh[co];
        const f32x4 acc = nt ? acc1 : acc0;
        #pragma unroll
        for (int r = 0; r < 4; ++r){
            float val = fmaxf(acc[r] * s + h, 0.f);
            val = ((m4 >> (8*r)) & 0xFFu) ? val : 0.f;
            out[(size_t)(vb + r) * 32 + co] = f2bf(val);
        }
    }
}

// ---- generic direct-global MFMA conv (down1); NSPLIT waves share one output tile's channels ----
template<int DIN, int DOUT, int CIN, int COUT, int STRIDE, int NSPLIT, bool FINAL>
__global__ __launch_bounds__(256)
void mconv_k(const u16* __restrict__ in, const u16* __restrict__ wf,
             const float* __restrict__ sc, const float* __restrict__ sh,
             const u8* __restrict__ mk, void* __restrict__ out,
             const u32* __restrict__ flag)
{
    constexpr int KC = CIN / 32;
    constexpr int NT = COUT / 16;
    constexpr int NTE = NT / NSPLIT;
    constexpr int XT = DOUT / 16;
    const int wjj = blockIdx.x * 4 + (threadIdx.x >> 6);
    const int cs = wjj % NSPLIT;
    const int wj = wjj / NSPLIT;
    const int lane = threadIdx.x & 63;
    const int m = lane & 15, quad = lane >> 4;

    const int xo_b = (wj % XT) * 16;
    const int yo = (wj / XT) % DOUT;
    const int zo = wj / (XT * DOUT);

    f32x4 acc[NTE];
    #pragma unroll
    for (int i = 0; i < NTE; ++i) acc[i] = (f32x4){0.f,0.f,0.f,0.f};

    const int ix0 = (xo_b + m) * STRIDE - 1;
    for (int kz = 0; kz < 3; ++kz){
      const int iz = zo * STRIDE + kz - 1;
      if ((unsigned)iz >= (unsigned)DIN) continue;
      for (int ky = 0; ky < 3; ++ky){
        const int iy = yo * STRIDE + ky - 1;
        if ((unsigned)iy >= (unsigned)DIN) continue;
        const size_t rowb = ((size_t)iz * DIN + iy) * DIN;
        #pragma unroll
        for (int kx = 0; kx < 3; ++kx){
          const int ix = ix0 + kx;
          const bool v = (unsigned)ix < (unsigned)DIN;
          const int tap = (kz*3 + ky)*3 + kx;
          const u16* ap = in + (rowb + ix) * CIN + quad * 8;
          const u16* bp = wf + (size_t)tap * KC * NT * 512 + lane * 8;
          #pragma unroll
          for (int kc = 0; kc < KC; ++kc){
            short8 a = {0,0,0,0,0,0,0,0};
            if (v) a = *(const short8*)(ap + kc * 32);
            #pragma unroll
            for (int nt = 0; nt < NTE; ++nt){
              short8 b = *(const short8*)(bp + (kc * NT + cs * NTE + nt) * 512);
              acc[nt] = __builtin_amdgcn_mfma_f32_16x16x32_bf16(a, b, acc[nt], 0, 0, 0);
            }
          }
    }}}

    const int vb = wj * 16 + quad * 4;
    const u32 m4 = *(const u32*)(mk + vb);
    const int n = lane & 15;
    #pragma unroll
    for (int nt = 0; nt < NTE; ++nt){
        const int co = (cs * NTE + nt) * 16 + n;
        const float s = sc[co], h = sh[co];
        #pragma unroll
        for (int r = 0; r < 4; ++r){
            float val = fmaxf(acc[nt][r] * s + h, 0.f);
            val = ((m4 >> (8*r)) & 0xFFu) ? val : 0.f;
            ((u16*)out)[(size_t)(vb + r) * COUT + co] = f2bf(val);
        }
    }
    (void)flag;
}

// ---- LDS-staged 16x16 MFMA conv, stride 1, 2x2 output rows per block, M=32/wave ----
// CSPLIT: waves split output channels. FOLD: measurement fold (0 = off).
template<int D, int CIN, int COUT, int CSPLIT, bool FINAL, int FOLD = 0>
__global__ __launch_bounds__((D/32)*4*64*CSPLIT)
void mconvw_k(const u16* __restrict__ in, const u16* __restrict__ wf,
              const float* __restrict__ sc, const float* __restrict__ sh,
              const u8* __restrict__ mk, void* __restrict__ out,
              const u32* __restrict__ flag)
{
    constexpr int KC = CIN / 32;
    constexpr int NT = COUT / 16;
    constexpr int NTE = NT / CSPLIT;
    constexpr int CH8 = CIN / 8;
    constexpr int WPR = D / 32;
    constexpr int BT = WPR * 4 * 64 * CSPLIT;
    __shared__ u16 tile[16 * 2048];

    int bx = (int)blockIdx.x;
    if (FOLD > 0 && bx >= FOLD) bx -= FOLD;

    const int t = threadIdx.x;
    const int yp = bx % (D / 2);
    const int zp = bx / (D / 2);

    #pragma unroll
    for (int ri = 0; ri < 16; ++ri){
        const int dz = ri >> 2, jy = ri & 3;
        const int iz = 2*zp + dz - 1, iy = 2*yp + jy - 1;
        if ((unsigned)iz < (unsigned)D && (unsigned)iy < (unsigned)D){
            const u16* src = in + ((size_t)(iz * D + iy) * D) * CIN;
            u16* dst = &tile[ri * 2048];
            for (int c = t; c < D * CH8; c += BT){
                const int x = c / CH8, c8 = c % CH8;
                *(short8*)(dst + (c8 * D + x) * 8) = *(const short8*)(src + c * 8);
            }
        }
    }
    __syncthreads();

    const int lane = t & 63, w = t >> 6;
    const int cs = w % CSPLIT;
    const int w2 = w / CSPLIT;
    const int r = w2 / WPR;
    const int r2z = r >> 1, r2y = r & 1;
    const int xo_b = (w2 % WPR) * 32;
    const int zo = 2*zp + r2z, yo = 2*yp + r2y;
    const int m = lane & 15, quad = lane >> 4;

    f32x4 acc0[NTE], acc1[NTE];
    #pragma unroll
    for (int i = 0; i < NTE; ++i){ acc0[i] = (f32x4){0.f,0.f,0.f,0.f}; acc1[i] = (f32x4){0.f,0.f,0.f,0.f}; }

    #pragma unroll
    for (int kz = 0; kz < 3; ++kz){
      const int iz = zo + kz - 1;
      if ((unsigned)iz >= (unsigned)D) continue;
      #pragma unroll
      for (int ky = 0; ky < 3; ++ky){
        const int iy = yo + ky - 1;
        if ((unsigned)iy >= (unsigned)D) continue;
        const u16* row = &tile[((r2z + kz) * 4 + (r2y + ky)) * 2048];
        #pragma unroll
        for (int kx = 0; kx < 3; ++kx){
          const int ix0 = xo_b + m + kx - 1;
          const int ix1 = ix0 + 16;
          const bool aok0 = (unsigned)ix0 < (unsigned)D;
          const bool aok1 = (unsigned)ix1 < (unsigned)D;
          const int tap = (kz * 3 + ky) * 3 + kx;
          const u16* bp = wf + (size_t)tap * KC * NT * 512 + lane * 8;
          #pragma unroll
          for (int kc = 0; kc < KC; ++kc){
            short8 a0 = {0,0,0,0,0,0,0,0};
            short8 a1 = {0,0,0,0,0,0,0,0};
            if (aok0) a0 = *(const short8*)(row + ((kc * 4 + quad) * D + ix0) * 8);
            if (aok1) a1 = *(const short8*)(row + ((kc * 4 + quad) * D + ix1) * 8);
            #pragma unroll
            for (int nt = 0; nt < NTE; ++nt){
              short8 b = *(const short8*)(bp + (kc * NT + cs * NTE + nt) * 512);
              acc0[nt] = __builtin_amdgcn_mfma_f32_16x16x32_bf16(a0, b, acc0[nt], 0, 0, 0);
              acc1[nt] = __builtin_amdgcn_mfma_f32_16x16x32_bf16(a1, b, acc1[nt], 0, 0, 0);
            }
          }
        }
      }
    }

    const int base = (zo * D + yo) * D;
    const int vb0 = base + xo_b + quad * 4;
    const int vb1 = vb0 + 16;
    const u32 m4_0 = *(const u32*)(mk + vb0);
    const u32 m4_1 = *(const u32*)(mk + vb1);
    const int n = lane & 15;
    if (FINAL) {
        const bool bfout = flag[0] != 0;
        #pragma unroll
        for (int nt = 0; nt < NTE; ++nt){
            const int co = (cs * NTE + nt) * 16 + n;
            const float s = sc[co], h = sh[co];
            float4 o0, o1;
            float* p0 = &o0.x; float* p1 = &o1.x;
            #pragma unroll
            for (int r4 = 0; r4 < 4; ++r4){
                float v0 = fmaxf(acc0[nt][r4] * s + h, 0.f);
                float v1 = fmaxf(acc1[nt][r4] * s + h, 0.f);
                p0[r4] = ((m4_0 >> (8*r4)) & 0xFFu) ? v0 : 0.f;
                p1[r4] = ((m4_1 >> (8*r4)) & 0xFFu) ? v1 : 0.f;
            }
            if (!bfout) {
                *(float4*)((float*)out + (size_t)co * (D*D*D) + vb0) = o0;
                *(float4*)((float*)out + (size_t)co * (D*D*D) + vb1) = o1;
            } else {
                u16* ob0 = (u16*)out + (size_t)co * (D*D*D) + vb0;
                u16* ob1 = (u16*)out + (size_t)co * (D*D*D) + vb1;
                #pragma unroll
                for (int r4 = 0; r4 < 4; ++r4){ ob0[r4] = f2bf(p0[r4]); ob1[r4] = f2bf(p1[r4]); }
            }
        }
    } else {
        #pragma unroll
        for (int nt = 0; nt < NTE; ++nt){
            const int co = (cs * NTE + nt) * 16 + n;
            const float s = sc[co], h = sh[co];
            #pragma unroll
            for (int r4 = 0; r4 < 4; ++r4){
                float v0 = fmaxf(acc0[nt][r4] * s + h, 0.f);
                float v1 = fmaxf(acc1[nt][r4] * s + h, 0.f);
                v0 = ((m4_0 >> (8*r4)) & 0xFFu) ? v0 : 0.f;
                v1 = ((m4_1 >> (8*r4)) & 0xFFu) ? v1 : 0.f;
                ((u16*)out)[(size_t)(vb0 + r4) * COUT + co] = f2bf(v0);
                ((u16*)out)[(size_t)(vb1 + r4) * COUT + co] = f2bf(v1);
            }
        }
    }
}

extern "C" void kernel_launch(void* const* d_in, const int* in_sizes, int n_in,
                              void* d_out, int out_size, void* d_ws, size_t ws_size,
                              hipStream_t stream)
{
    (void)out_size; (void)ws_size;

    int wb = 2;
    for (int i = 1; i < n_in; ++i) { if (in_sizes[i] == 6912) { wb = i; break; } }

    const void* x = d_in[0];
    const void *w0a=d_in[wb+0],  *s0a=d_in[wb+1],  *b0a=d_in[wb+2];
    const void *w0b=d_in[wb+3],  *s0b=d_in[wb+4],  *b0b=d_in[wb+5];
    const void *wd0=d_in[wb+6],  *sd0=d_in[wb+7],  *bd0=d_in[wb+8];
    const void *w1a=d_in[wb+9],  *s1a=d_in[wb+10], *b1a=d_in[wb+11];
    const void *w1b=d_in[wb+12], *s1b=d_in[wb+13], *b1b=d_in[wb+14];
    const void *wd1=d_in[wb+15], *sd1=d_in[wb+16], *bd1=d_in[wb+17];
    const void *w2a=d_in[wb+18], *s2a=d_in[wb+19], *b2a=d_in[wb+20];
    const void *w2b=d_in[wb+21], *s2b=d_in[wb+22], *b2b=d_in[wb+23];
    const void *w2c=d_in[wb+24], *s2c=d_in[wb+25], *b2c=d_in[wb+26];

    // ---- workspace layout (~128 MiB of 512) ----
    char* ws = (char*)d_ws;
    int*   idxmap = (int*)(ws);                     //  8,388,608
    u16*   Fb0    = (u16*)(ws + 8388608);           //  4,194,304
    u16*   Fb1    = (u16*)(ws + 12582912);          //  4,194,304
    u16*   Fb2    = (u16*)(ws + 16777216);          //  4,194,304
    u16*   Rb1    = (u16*)(ws + 25165824);          // 16,777,216
    u16*   Rb2    = (u16*)(ws + 41943040);          // 16,777,216
    u8*    m1     = (u8*)(ws + 58720256);           //    262,144
    u8*    m2     = (u8*)(ws + 58982400);           //     32,768
    u32*   cnt    = (u32*)(ws + 59015168);          //        256
    int*   alist  = (int*)(ws + 59015424);          //    524,288
    u16*   FR     = (u16*)(ws + 59539712);          //    943,616
    float* S      = (float*)(ws + 60483328);        //      3,072
    u32*   flag   = (u32*)(ws + 60486400);          //        256
    u64*   bmask  = (u64*)(ws + 60486656);          //    262,144
    u16*   Xp     = (u16*)(ws + 67108864);          // 67,108,864 (block-packed features)

    u16* wfs0a = FR + 0;
    u16* wfs0b = FR + 7168;
    u16* fd0   = FR + 14336;
    u16* f1a   = FR + 28672;
    u16* f1b   = FR + 56320;
    u16* fd1   = FR + 83968;
    u16* f2a   = FR + 139264;
    u16* f2b   = FR + 249856;
    u16* f2c   = FR + 360448;

    PAll J;
    const void* jsrc[9] = {w0a, w0b, wd0, w1a, w1b, wd1, w2a, w2b, w2c};
    const u32 jlen[9]   = {7168,7168,14336,27648,27648,55296,110592,110592,110592};
    const int jcin[9]   = {16,16,16,32,32,32,64,64,64};
    const int jcout[9]  = {16,16,32,32,32,64,64,64,64};
    const int jmode[9]  = {2,2,1,0,0,0,0,0,0};
    u32 acc = 0;
    for (int i = 0; i < 9; ++i){
        J.w[i] = jsrc[i]; J.wstart[i] = acc; acc += jlen[i];
        J.cin[i] = jcin[i]; J.cout[i] = jcout[i]; J.mode[i] = jmode[i];
    }
    J.wstart[9] = acc;
    const void* sv[18] = {s0a,b0a,s0b,b0b,sd0,bd0,s1a,b1a,s1b,b1b,sd1,bd1,s2a,b2a,s2b,b2b,s2c,b2c};
    for (int i = 0; i < 18; ++i) J.s[i] = sv[i];
    const u32 ptot = acc + 768;
    const int prep_blocks = (int)((ptot + 255) / 256);

    float *cs0a=S+0,  *cb0a=S+16,  *cs0b=S+32,  *cb0b=S+48;
    float *csd0=S+64, *cbd0=S+96,  *cs1a=S+128, *cb1a=S+160, *cs1b=S+192, *cb1b=S+224;
    float *csd1=S+256,*cbd1=S+320, *cs2a=S+384, *cb2a=S+448, *cs2b=S+512, *cb2b=S+576, *cs2c=S+640, *cb2c=S+704;

    // 10 graph nodes; MEASUREMENT ROUND: sconv-a, down0, 64^3-a grids doubled (fold
    // recomputes identical outputs) so their true in-kernel times surface in dur_us
    // and, if >79us doubled, in the top-5 counter rows.
    prepact_k<<<8192 + prep_blocks, 256, 0, stream>>>(J, FR, S, (const u16*)s0a, flag,
                                                      x, bmask, cnt, Xp);
    scatter2m_k<<<1664, 256, 0, stream>>>(Xp, bmask, idxmap, alist, Fb0, cnt, m1, m2);

    // stage A (128^3, 16ch, ~5% active) — a-layer grid DOUBLED (4096, folds to 2048)
    sconvm_k<<<4096, 256, 0, stream>>>(Fb0, idxmap, alist, cnt, wfs0a, cs0a, cb0a, Fb1);
    sconvm_k<<<2048, 256, 0, stream>>>(Fb1, idxmap, alist, cnt, wfs0b, cs0b, cb0b, Fb2);
    // down0 — grid DOUBLED (8192, folds to 4096)
    convd0m_k<<<8192, 256, 0, stream>>>(Fb2, idxmap, fd0, csd0, cbd0, m1, Rb1);
    // 64^3 stage — a-layer grid DOUBLED (2048, folds to 1024)
    mconvw_k<64,32,32,1,false,1024><<<2048, 512, 0, stream>>>(Rb1, f1a, cs1a, cb1a, m1, Rb2, flag);
    mconvw_k<64,32,32,1,false,0><<<1024, 512, 0, stream>>>(Rb2, f1b, cs1b, cb1b, m1, Rb1, flag);
    // down1 -> 32^3 x 64 (stride 2, NSPLIT=2)
    mconv_k<64,32,32,64,2,2,false><<<1024, 256, 0, stream>>>(Rb1, fd1, csd1, cbd1, m2, Rb2, flag);
    // 32^3 stage — CSPLIT=2
    mconvw_k<32,64,64,2,false,0><<<256, 512, 0, stream>>>(Rb2, f2a, cs2a, cb2a, m2, Rb1, flag);
    mconvw_k<32,64,64,2,false,0><<<256, 512, 0, stream>>>(Rb1, f2b, cs2b, cb2b, m2, Rb2, flag);
    // final conv: NCDHW f32 (or bf16 per flag) to d_out
    mconvw_k<32,64,64,2,true,0><<<256, 512, 0, stream>>>(Rb2, f2c, cs2c, cb2c, m2, d_out, flag);
}

// Round 8
// 495.006 us; speedup vs baseline: 1.0579x; 1.0579x over previous
//
#include <hip/hip_runtime.h>
#include <cstdint>

typedef unsigned short u16;
typedef unsigned int u32;
typedef unsigned char u8;
typedef unsigned long long u64;
typedef __attribute__((ext_vector_type(8))) short short8;
typedef __attribute__((ext_vector_type(4))) float f32x4;

#define CAP 131072  // max compact slots at 128^3 (~105k expected active)

__device__ __forceinline__ float bf1(u16 v){ union{u32 i; float f;} c; c.i = ((u32)v) << 16; return c.f; }
__device__ __forceinline__ u16 f2bf(float f){
    union{float f; u32 i;} c; c.f = f; u32 i = c.i;
    return (u16)((i + 0x7FFFu + ((i >> 16) & 1u)) >> 16);   // RTNE
}
__device__ __forceinline__ u16 bits2bf(u32 b){ union{u32 i; float f;} c; c.i = b; return f2bf(c.f); }

struct PAll {
    const void* w[9];
    u32 wstart[10];
    int cin[9], cout[9], mode[9];   // 0=16x16 wfrag, 1=d0 pair(16->32), 2=subm0 pair(16->16)
    const void* s[18];
};

// ---- dispatch-overhead probe: effectively empty kernel (never-taken guard) ----
__global__ __launch_bounds__(256)
void null_k(const u32* __restrict__ flag){
    if (flag[0] == 0xDEADBEEFu) {     // flag is only ever 0 or 1
        __threadfence();
    }
}

// ---- fused phase 0+1: blocks [0,8192) = active bitmask + packed features;
// blocks [8192,..) = weight-fragment + scale prep. Flag self-derived per thread. ----
__global__ __launch_bounds__(256)
void prepact_k(PAll J, u16* __restrict__ FR, float* __restrict__ S,
               const u16* __restrict__ s0a_probe, u32* __restrict__ flag,
               const void* __restrict__ xv, u64* __restrict__ bmask,
               u32* __restrict__ cnt, u16* __restrict__ Xp){
    int ok = 1;
    #pragma unroll
    for (int i = 0; i < 8; i += 2){
        u16 vv = s0a_probe[i];
        if (vv < 0x3F00u || vv > 0x3FC0u) ok = 0;
    }
    const u32 isbf = ok ? 1u : 0u;

    if (blockIdx.x < 8192){
        const int v = blockIdx.x * 256 + threadIdx.x;
        const size_t N = 2097152;
        u16 vals[16];
        u32 a = 0;
        if (isbf) {
            const u16* x = (const u16*)xv;
            #pragma unroll
            for (int c = 0; c < 16; ++c){
                const u16 b = x[(size_t)c * N + v];
                vals[c] = b;
                a |= (u32)b & 0x7FFFu;
            }
        } else {
            const u32* x = (const u32*)xv;
            #pragma unroll
            for (int c = 0; c < 16; ++c){
                const u32 b = x[(size_t)c * N + v];
                vals[c] = bits2bf(b);
                a |= b & 0x7FFFFFFFu;
            }
        }
        const bool act = (a != 0);
        const u64 m = __ballot(act);
        __shared__ u32 wc[4];
        const int lane = threadIdx.x & 63, wv = threadIdx.x >> 6;
        if (lane == 0) { bmask[v >> 6] = m; wc[wv] = (u32)__popcll(m); }
        __syncthreads();
        if (act){
            u32 wbase = 0;
            for (int i = 0; i < wv; ++i) wbase += wc[i];
            const u32 local = wbase + (u32)__popcll(m & ((1ull << lane) - 1ull));
            u16* dst = Xp + ((size_t)blockIdx.x * 256 + local) * 16;
            *(short8*)(dst)     = *(const short8*)(vals);
            *(short8*)(dst + 8) = *(const short8*)(vals + 8);
        }
        return;
    }

    const int gi = (int)(blockIdx.x - 8192) * 256 + threadIdx.x;
    if (gi == 0) { flag[0] = isbf; cnt[0] = 0; }

    const int wtot = (int)J.wstart[9];
    if (gi < wtot){
        int j = 0;
        while (gi >= (int)J.wstart[j + 1]) ++j;
        const int i = gi - (int)J.wstart[j];
        const void* w = J.w[j];
        const int CIN = J.cin[j], COUT = J.cout[j];
        const int jj = i & 7;
        const int lane = (i >> 3) & 63;
        int rest = i >> 9;
        int src = -1;
        if (J.mode[j] == 0){
            const int KC = CIN >> 5, NT = COUT >> 4;
            const int nt = rest % NT; rest /= NT;
            const int kc = rest % KC; const int tap = rest / KC;
            const int k = kc * 32 + (lane >> 4) * 8 + jj;
            const int co = nt * 16 + (lane & 15);
            src = (tap * CIN + k) * COUT + co;
        } else if (J.mode[j] == 1){
            const int nt = rest & 1; const int pair = rest >> 1;
            const int kg = (lane >> 4) * 8 + jj;
            const int tap = pair * 2 + (kg >> 4);
            const int ci = kg & 15;
            const int co = nt * 16 + (lane & 15);
            if (tap < 27) src = (tap * 16 + ci) * 32 + co;
        } else {
            const int pair = rest;
            const int kg = (lane >> 4) * 8 + jj;
            const int tap = pair * 2 + (kg >> 4);
            const int ci = kg & 15;
            const int co = lane & 15;
            if (tap < 27) src = (tap * 16 + ci) * 16 + co;
        }
        float v = 0.f;
        if (src >= 0) v = isbf ? bf1(((const u16*)w)[src]) : ((const float*)w)[src];
        FR[gi] = f2bf(v);
    } else {
        const int i2 = gi - wtot;
        const int len[18] = {16,16,16,16,32,32,32,32,32,32,64,64,64,64,64,64,64,64};
        const int off[18] = {0,16,32,48,64,96,128,160,192,224,256,320,384,448,512,576,640,704};
        if (i2 < 768){
            int b = 0, base = 0;
            while (i2 >= base + len[b]) { base += len[b]; ++b; }
            const int t = i2 - base;
            const float v = isbf ? bf1(((const u16*)J.s[b])[t]) : ((const float*)J.s[b])[t];
            S[off[b] + t] = v;
        }
    }
}

// ---- fused: scatter (16 tiles/block, ONE atomic per block) + m1 + m2 from bmask ----
// blocks [0,512): scatter; [512,1536): m1; [1536,1664): m2
__global__ __launch_bounds__(256)
void scatter2m_k(const u16* __restrict__ Xp, const u64* __restrict__ bmask,
                 int* __restrict__ idxmap, int* __restrict__ alist,
                 u16* __restrict__ f, u32* __restrict__ cnt,
                 u8* __restrict__ m1, u8* __restrict__ m2){
    if (blockIdx.x < 512){
        const int lane = threadIdx.x & 63, wv = threadIdx.x >> 6;
        __shared__ u32 wcnt[16][4];
        __shared__ u32 tileoff[16];
        __shared__ u32 sbase;
        const int tile0 = blockIdx.x * 16;

        #pragma unroll
        for (int i = 0; i < 16; ++i){
            if (lane == 0){
                const u64 m = bmask[(size_t)(tile0 + i) * 4 + wv];
                wcnt[i][wv] = (u32)__popcll(m);
            }
        }
        __syncthreads();
        if (threadIdx.x == 0){
            u32 s = 0;
            #pragma unroll
            for (int i = 0; i < 16; ++i){
                tileoff[i] = s;
                s += wcnt[i][0] + wcnt[i][1] + wcnt[i][2] + wcnt[i][3];
            }
            sbase = atomicAdd(cnt, s);
        }
        __syncthreads();
        const u32 b0 = sbase;
        #pragma unroll
        for (int i = 0; i < 16; ++i){
            const u64 m = bmask[(size_t)(tile0 + i) * 4 + wv];
            const bool act = (m >> lane) & 1ull;
            u32 wbase = 0;
            for (int k = 0; k < wv; ++k) wbase += wcnt[i][k];
            const u32 rank = (u32)__popcll(m & ((1ull << lane) - 1ull));
            const int v = (tile0 + i) * 256 + threadIdx.x;
            int slot = -1;
            if (act){
                const u32 sl = b0 + tileoff[i] + wbase + rank;
                if (sl < CAP){
                    slot = (int)sl;
                    alist[slot] = v;
                    const u16* src = Xp + ((size_t)(tile0 + i) * 256 + wbase + rank) * 16;
                    u16* dst = f + (size_t)slot * 16;
                    *(short8*)(dst)     = *(const short8*)(src);
                    *(short8*)(dst + 8) = *(const short8*)(src + 8);
                }
            }
            idxmap[v] = slot;
        }
    } else if (blockIdx.x < 1536){
        const int v = (int)(blockIdx.x - 512) * 256 + threadIdx.x;
        const int xo = v & 63, yo = (v >> 6) & 63, zo = v >> 12;
        u32 a = 0;
        #pragma unroll
        for (int kz = 0; kz < 3; ++kz){ const int iz = 2*zo + kz - 1; if ((unsigned)iz >= 128u) continue;
          #pragma unroll
          for (int ky = 0; ky < 3; ++ky){ const int iy = 2*yo + ky - 1; if ((unsigned)iy >= 128u) continue;
            #pragma unroll
            for (int kx = 0; kx < 3; ++kx){ const int ix = 2*xo + kx - 1; if ((unsigned)ix >= 128u) continue;
              const int vv = (iz * 128 + iy) * 128 + ix;
              a |= (u32)((bmask[vv >> 6] >> (vv & 63)) & 1ull);
        }}}
        m1[v] = (u8)a;
    } else {
        const int v = (int)(blockIdx.x - 1536) * 256 + threadIdx.x;
        const int xo = v & 31, yo = (v >> 5) & 31, zo = v >> 10;
        const int xlo = max(0, 4*xo - 3), xhi = min(127, 4*xo + 3);
        const int w0 = xlo >> 6, w1 = xhi >> 6;
        u32 a = 0;
        #pragma unroll
        for (int dz = -3; dz <= 3; ++dz){ const int iz = 4*zo + dz; if ((unsigned)iz >= 128u) continue;
          #pragma unroll
          for (int dy = -3; dy <= 3; ++dy){ const int iy = 4*yo + dy; if ((unsigned)iy >= 128u) continue;
            const int rowword = ((iz * 128 + iy) * 128) >> 6;
            if (w0 == w1){
                const u64 mw = bmask[rowword + w0];
                const int sh = xlo & 63, len = xhi - xlo + 1;
                if ((mw >> sh) & ((1ull << len) - 1ull)) a = 1;
            } else {
                const u64 lo = bmask[rowword + w0] >> (xlo & 63);
                const u64 hi = bmask[rowword + w1] & ((1ull << ((xhi & 63) + 1)) - 1ull);
                if (lo | hi) a = 1;
            }
        }}
        m2[v] = (u8)a;
    }
}

// ---- MFMA sparse subm conv at 128^3: compact bf16 16ch -> 16ch ----
__global__ __launch_bounds__(256)
void sconvm_k(const u16* __restrict__ fin, const int* __restrict__ idxmap,
              const int* __restrict__ alist, const u32* __restrict__ cnt,
              const u16* __restrict__ wf, const float* __restrict__ sc,
              const float* __restrict__ sh, u16* __restrict__ fout){
    const int n = min((int)cnt[0], CAP);
    const int bx = (int)(blockIdx.x & 2047u);   // identity at grid 2048
    const int j = bx * 4 + (threadIdx.x >> 6);
    const int sbase = j * 16;
    if (sbase >= n) return;
    const int lane = threadIdx.x & 63;
    const int m = lane & 15, quad = lane >> 4;

    const int s = sbase + m;
    const int v = (s < n) ? alist[s] : -1;
    int xo = 0, yo = 0, zo = 0;
    if (v >= 0){ xo = v & 127; yo = (v >> 7) & 127; zo = v >> 14; }

    int sn[14];
    #pragma unroll
    for (int p = 0; p < 14; ++p){
        const int tp = p * 2 + (quad >> 1);
        int sv = -1;
        if (v >= 0 && tp < 27){
            const int kz = tp / 9, ky = (tp / 3) % 3, kx = tp % 3;
            const int iz = zo + kz - 1, iy = yo + ky - 1, ix = xo + kx - 1;
            if ((unsigned)iz < 128u && (unsigned)iy < 128u && (unsigned)ix < 128u){
                sv = idxmap[((size_t)iz * 128 + iy) * 128 + ix];
            }
        }
        sn[p] = sv;
    }

    f32x4 acc = {0.f,0.f,0.f,0.f};
    #pragma unroll
    for (int p = 0; p < 14; ++p){
        short8 a = {0,0,0,0,0,0,0,0};
        if (sn[p] >= 0) a = *(const short8*)(fin + (size_t)sn[p] * 16 + (quad & 1) * 8);
        short8 b = *(const short8*)(wf + ((size_t)p * 64 + lane) * 8);
        acc = __builtin_amdgcn_mfma_f32_16x16x32_bf16(a, b, acc, 0, 0, 0);
    }

    const int co = lane & 15;
    const float scl = sc[co], shf = sh[co];
    #pragma unroll
    for (int r = 0; r < 4; ++r){
        const int srow = sbase + quad * 4 + r;
        if (srow < n){
            fout[(size_t)srow * 16 + co] = f2bf(fmaxf(acc[r] * scl + shf, 0.f));
        }
    }
}

// ---- down0 MFMA: compact bf16 16ch @128^3 -> bf16 NDHWC 32ch @64^3 ----
__global__ __launch_bounds__(256)
void convd0m_k(const u16* __restrict__ fbuf, const int* __restrict__ idxmap,
               const u16* __restrict__ wf, const float* __restrict__ sc,
               const float* __restrict__ sh, const u8* __restrict__ mk,
               u16* __restrict__ out)
{
    const int bx = (int)(blockIdx.x & 4095u);   // identity at grid 4096
    const int wj = bx * 4 + (threadIdx.x >> 6);
    const int lane = threadIdx.x & 63;
    const int m = lane & 15, quad = lane >> 4;
    const int xo_b = (wj & 3) * 16;
    const int yo = (wj >> 2) & 63;
    const int zo = wj >> 8;
    const int ix_m = (xo_b + m) * 2 - 1;

    int sn[14];
    #pragma unroll
    for (int p = 0; p < 14; ++p){
        const int tp = p * 2 + (quad >> 1);
        int sv = -1;
        if (tp < 27){
            const int kz = tp / 9, ky = (tp / 3) % 3, kx = tp % 3;
            const int iz = 2*zo + kz - 1, iy = 2*yo + ky - 1, ix = ix_m + kx;
            if ((unsigned)iz < 128u && (unsigned)iy < 128u && (unsigned)ix < 128u){
                sv = idxmap[((size_t)iz * 128 + iy) * 128 + ix];
            }
        }
        sn[p] = sv;
    }

    f32x4 acc0 = {0.f,0.f,0.f,0.f}, acc1 = {0.f,0.f,0.f,0.f};
    #pragma unroll
    for (int p = 0; p < 14; ++p){
        short8 a = {0,0,0,0,0,0,0,0};
        if (sn[p] >= 0) a = *(const short8*)(fbuf + (size_t)sn[p] * 16 + (quad & 1) * 8);
        short8 b0 = *(const short8*)(wf + ((size_t)(p*2+0) * 64 + lane) * 8);
        short8 b1 = *(const short8*)(wf + ((size_t)(p*2+1) * 64 + lane) * 8);
        acc0 = __builtin_amdgcn_mfma_f32_16x16x32_bf16(a, b0, acc0, 0, 0, 0);
        acc1 = __builtin_amdgcn_mfma_f32_16x16x32_bf16(a, b1, acc1, 0, 0, 0);
    }

    const int vb = wj * 16 + quad * 4;
    const u32 m4 = *(const u32*)(mk + vb);
    const int n = lane & 15;
    #pragma unroll
    for (int nt = 0; nt < 2; ++nt){
        const int co = nt * 16 + n;
        const float s = sc[co], h = sh[co];
        const f32x4 acc = nt ? acc1 : acc0;
        #pragma unroll
        for (int r = 0; r < 4; ++r){
            float val = fmaxf(acc[r] * s + h, 0.f);
            val = ((m4 >> (8*r)) & 0xFFu) ? val : 0.f;
            out[(size_t)(vb + r) * 32 + co] = f2bf(val);
        }
    }
}

// ---- generic direct-global MFMA conv (down1); NSPLIT waves share one output tile's channels ----
template<int DIN, int DOUT, int CIN, int COUT, int STRIDE, int NSPLIT, bool FINAL>
__global__ __launch_bounds__(256)
void mconv_k(const u16* __restrict__ in, const u16* __restrict__ wf,
             const float* __restrict__ sc, const float* __restrict__ sh,
             const u8* __restrict__ mk, void* __restrict__ out,
             const u32* __restrict__ flag)
{
    constexpr int KC = CIN / 32;
    constexpr int NT = COUT / 16;
    constexpr int NTE = NT / NSPLIT;
    constexpr int XT = DOUT / 16;
    const int wjj = blockIdx.x * 4 + (threadIdx.x >> 6);
    const int cs = wjj % NSPLIT;
    const int wj = wjj / NSPLIT;
    const int lane = threadIdx.x & 63;
    const int m = lane & 15, quad = lane >> 4;

    const int xo_b = (wj % XT) * 16;
    const int yo = (wj / XT) % DOUT;
    const int zo = wj / (XT * DOUT);

    f32x4 acc[NTE];
    #pragma unroll
    for (int i = 0; i < NTE; ++i) acc[i] = (f32x4){0.f,0.f,0.f,0.f};

    const int ix0 = (xo_b + m) * STRIDE - 1;
    for (int kz = 0; kz < 3; ++kz){
      const int iz = zo * STRIDE + kz - 1;
      if ((unsigned)iz >= (unsigned)DIN) continue;
      for (int ky = 0; ky < 3; ++ky){
        const int iy = yo * STRIDE + ky - 1;
        if ((unsigned)iy >= (unsigned)DIN) continue;
        const size_t rowb = ((size_t)iz * DIN + iy) * DIN;
        #pragma unroll
        for (int kx = 0; kx < 3; ++kx){
          const int ix = ix0 + kx;
          const bool v = (unsigned)ix < (unsigned)DIN;
          const int tap = (kz*3 + ky)*3 + kx;
          const u16* ap = in + (rowb + ix) * CIN + quad * 8;
          const u16* bp = wf + (size_t)tap * KC * NT * 512 + lane * 8;
          #pragma unroll
          for (int kc = 0; kc < KC; ++kc){
            short8 a = {0,0,0,0,0,0,0,0};
            if (v) a = *(const short8*)(ap + kc * 32);
            #pragma unroll
            for (int nt = 0; nt < NTE; ++nt){
              short8 b = *(const short8*)(bp + (kc * NT + cs * NTE + nt) * 512);
              acc[nt] = __builtin_amdgcn_mfma_f32_16x16x32_bf16(a, b, acc[nt], 0, 0, 0);
            }
          }
    }}}

    const int vb = wj * 16 + quad * 4;
    const u32 m4 = *(const u32*)(mk + vb);
    const int n = lane & 15;
    #pragma unroll
    for (int nt = 0; nt < NTE; ++nt){
        const int co = (cs * NTE + nt) * 16 + n;
        const float s = sc[co], h = sh[co];
        #pragma unroll
        for (int r = 0; r < 4; ++r){
            float val = fmaxf(acc[nt][r] * s + h, 0.f);
            val = ((m4 >> (8*r)) & 0xFFu) ? val : 0.f;
            ((u16*)out)[(size_t)(vb + r) * COUT + co] = f2bf(val);
        }
    }
    (void)flag;
}

// ---- LDS-staged 16x16 MFMA conv, stride 1, 2x2 output rows per block, M=32/wave ----
template<int D, int CIN, int COUT, int CSPLIT, bool FINAL, int FOLD = 0>
__global__ __launch_bounds__((D/32)*4*64*CSPLIT)
void mconvw_k(const u16* __restrict__ in, const u16* __restrict__ wf,
              const float* __restrict__ sc, const float* __restrict__ sh,
              const u8* __restrict__ mk, void* __restrict__ out,
              const u32* __restrict__ flag)
{
    constexpr int KC = CIN / 32;
    constexpr int NT = COUT / 16;
    constexpr int NTE = NT / CSPLIT;
    constexpr int CH8 = CIN / 8;
    constexpr int WPR = D / 32;
    constexpr int BT = WPR * 4 * 64 * CSPLIT;
    __shared__ u16 tile[16 * 2048];

    int bx = (int)blockIdx.x;
    if (FOLD > 0 && bx >= FOLD) bx -= FOLD;

    const int t = threadIdx.x;
    const int yp = bx % (D / 2);
    const int zp = bx / (D / 2);

    #pragma unroll
    for (int ri = 0; ri < 16; ++ri){
        const int dz = ri >> 2, jy = ri & 3;
        const int iz = 2*zp + dz - 1, iy = 2*yp + jy - 1;
        if ((unsigned)iz < (unsigned)D && (unsigned)iy < (unsigned)D){
            const u16* src = in + ((size_t)(iz * D + iy) * D) * CIN;
            u16* dst = &tile[ri * 2048];
            for (int c = t; c < D * CH8; c += BT){
                const int x = c / CH8, c8 = c % CH8;
                *(short8*)(dst + (c8 * D + x) * 8) = *(const short8*)(src + c * 8);
            }
        }
    }
    __syncthreads();

    const int lane = t & 63, w = t >> 6;
    const int cs = w % CSPLIT;
    const int w2 = w / CSPLIT;
    const int r = w2 / WPR;
    const int r2z = r >> 1, r2y = r & 1;
    const int xo_b = (w2 % WPR) * 32;
    const int zo = 2*zp + r2z, yo = 2*yp + r2y;
    const int m = lane & 15, quad = lane >> 4;

    f32x4 acc0[NTE], acc1[NTE];
    #pragma unroll
    for (int i = 0; i < NTE; ++i){ acc0[i] = (f32x4){0.f,0.f,0.f,0.f}; acc1[i] = (f32x4){0.f,0.f,0.f,0.f}; }

    #pragma unroll
    for (int kz = 0; kz < 3; ++kz){
      const int iz = zo + kz - 1;
      if ((unsigned)iz >= (unsigned)D) continue;
      #pragma unroll
      for (int ky = 0; ky < 3; ++ky){
        const int iy = yo + ky - 1;
        if ((unsigned)iy >= (unsigned)D) continue;
        const u16* row = &tile[((r2z + kz) * 4 + (r2y + ky)) * 2048];
        #pragma unroll
        for (int kx = 0; kx < 3; ++kx){
          const int ix0 = xo_b + m + kx - 1;
          const int ix1 = ix0 + 16;
          const bool aok0 = (unsigned)ix0 < (unsigned)D;
          const bool aok1 = (unsigned)ix1 < (unsigned)D;
          const int tap = (kz * 3 + ky) * 3 + kx;
          const u16* bp = wf + (size_t)tap * KC * NT * 512 + lane * 8;
          #pragma unroll
          for (int kc = 0; kc < KC; ++kc){
            short8 a0 = {0,0,0,0,0,0,0,0};
            short8 a1 = {0,0,0,0,0,0,0,0};
            if (aok0) a0 = *(const short8*)(row + ((kc * 4 + quad) * D + ix0) * 8);
            if (aok1) a1 = *(const short8*)(row + ((kc * 4 + quad) * D + ix1) * 8);
            #pragma unroll
            for (int nt = 0; nt < NTE; ++nt){
              short8 b = *(const short8*)(bp + (kc * NT + cs * NTE + nt) * 512);
              acc0[nt] = __builtin_amdgcn_mfma_f32_16x16x32_bf16(a0, b, acc0[nt], 0, 0, 0);
              acc1[nt] = __builtin_amdgcn_mfma_f32_16x16x32_bf16(a1, b, acc1[nt], 0, 0, 0);
            }
          }
        }
      }
    }

    const int base = (zo * D + yo) * D;
    const int vb0 = base + xo_b + quad * 4;
    const int vb1 = vb0 + 16;
    const u32 m4_0 = *(const u32*)(mk + vb0);
    const u32 m4_1 = *(const u32*)(mk + vb1);
    const int n = lane & 15;
    if (FINAL) {
        const bool bfout = flag[0] != 0;
        #pragma unroll
        for (int nt = 0; nt < NTE; ++nt){
            const int co = (cs * NTE + nt) * 16 + n;
            const float s = sc[co], h = sh[co];
            float4 o0, o1;
            float* p0 = &o0.x; float* p1 = &o1.x;
            #pragma unroll
            for (int r4 = 0; r4 < 4; ++r4){
                float v0 = fmaxf(acc0[nt][r4] * s + h, 0.f);
                float v1 = fmaxf(acc1[nt][r4] * s + h, 0.f);
                p0[r4] = ((m4_0 >> (8*r4)) & 0xFFu) ? v0 : 0.f;
                p1[r4] = ((m4_1 >> (8*r4)) & 0xFFu) ? v1 : 0.f;
            }
            if (!bfout) {
                *(float4*)((float*)out + (size_t)co * (D*D*D) + vb0) = o0;
                *(float4*)((float*)out + (size_t)co * (D*D*D) + vb1) = o1;
            } else {
                u16* ob0 = (u16*)out + (size_t)co * (D*D*D) + vb0;
                u16* ob1 = (u16*)out + (size_t)co * (D*D*D) + vb1;
                #pragma unroll
                for (int r4 = 0; r4 < 4; ++r4){ ob0[r4] = f2bf(p0[r4]); ob1[r4] = f2bf(p1[r4]); }
            }
        }
    } else {
        #pragma unroll
        for (int nt = 0; nt < NTE; ++nt){
            const int co = (cs * NTE + nt) * 16 + n;
            const float s = sc[co], h = sh[co];
            #pragma unroll
            for (int r4 = 0; r4 < 4; ++r4){
                float v0 = fmaxf(acc0[nt][r4] * s + h, 0.f);
                float v1 = fmaxf(acc1[nt][r4] * s + h, 0.f);
                v0 = ((m4_0 >> (8*r4)) & 0xFFu) ? v0 : 0.f;
                v1 = ((m4_1 >> (8*r4)) & 0xFFu) ? v1 : 0.f;
                ((u16*)out)[(size_t)(vb0 + r4) * COUT + co] = f2bf(v0);
                ((u16*)out)[(size_t)(vb1 + r4) * COUT + co] = f2bf(v1);
            }
        }
    }
}

extern "C" void kernel_launch(void* const* d_in, const int* in_sizes, int n_in,
                              void* d_out, int out_size, void* d_ws, size_t ws_size,
                              hipStream_t stream)
{
    (void)out_size; (void)ws_size;

    int wb = 2;
    for (int i = 1; i < n_in; ++i) { if (in_sizes[i] == 6912) { wb = i; break; } }

    const void* x = d_in[0];
    const void *w0a=d_in[wb+0],  *s0a=d_in[wb+1],  *b0a=d_in[wb+2];
    const void *w0b=d_in[wb+3],  *s0b=d_in[wb+4],  *b0b=d_in[wb+5];
    const void *wd0=d_in[wb+6],  *sd0=d_in[wb+7],  *bd0=d_in[wb+8];
    const void *w1a=d_in[wb+9],  *s1a=d_in[wb+10], *b1a=d_in[wb+11];
    const void *w1b=d_in[wb+12], *s1b=d_in[wb+13], *b1b=d_in[wb+14];
    const void *wd1=d_in[wb+15], *sd1=d_in[wb+16], *bd1=d_in[wb+17];
    const void *w2a=d_in[wb+18], *s2a=d_in[wb+19], *b2a=d_in[wb+20];
    const void *w2b=d_in[wb+21], *s2b=d_in[wb+22], *b2b=d_in[wb+23];
    const void *w2c=d_in[wb+24], *s2c=d_in[wb+25], *b2c=d_in[wb+26];

    // ---- workspace layout (~128 MiB of 512) ----
    char* ws = (char*)d_ws;
    int*   idxmap = (int*)(ws);                     //  8,388,608
    u16*   Fb0    = (u16*)(ws + 8388608);           //  4,194,304
    u16*   Fb1    = (u16*)(ws + 12582912);          //  4,194,304
    u16*   Fb2    = (u16*)(ws + 16777216);          //  4,194,304
    u16*   Rb1    = (u16*)(ws + 25165824);          // 16,777,216
    u16*   Rb2    = (u16*)(ws + 41943040);          // 16,777,216
    u8*    m1     = (u8*)(ws + 58720256);           //    262,144
    u8*    m2     = (u8*)(ws + 58982400);           //     32,768
    u32*   cnt    = (u32*)(ws + 59015168);          //        256
    int*   alist  = (int*)(ws + 59015424);          //    524,288
    u16*   FR     = (u16*)(ws + 59539712);          //    943,616
    float* S      = (float*)(ws + 60483328);        //      3,072
    u32*   flag   = (u32*)(ws + 60486400);          //        256
    u64*   bmask  = (u64*)(ws + 60486656);          //    262,144
    u16*   Xp     = (u16*)(ws + 67108864);          // 67,108,864 (block-packed features)

    u16* wfs0a = FR + 0;
    u16* wfs0b = FR + 7168;
    u16* fd0   = FR + 14336;
    u16* f1a   = FR + 28672;
    u16* f1b   = FR + 56320;
    u16* fd1   = FR + 83968;
    u16* f2a   = FR + 139264;
    u16* f2b   = FR + 249856;
    u16* f2c   = FR + 360448;

    PAll J;
    const void* jsrc[9] = {w0a, w0b, wd0, w1a, w1b, wd1, w2a, w2b, w2c};
    const u32 jlen[9]   = {7168,7168,14336,27648,27648,55296,110592,110592,110592};
    const int jcin[9]   = {16,16,16,32,32,32,64,64,64};
    const int jcout[9]  = {16,16,32,32,32,64,64,64,64};
    const int jmode[9]  = {2,2,1,0,0,0,0,0,0};
    u32 acc = 0;
    for (int i = 0; i < 9; ++i){
        J.w[i] = jsrc[i]; J.wstart[i] = acc; acc += jlen[i];
        J.cin[i] = jcin[i]; J.cout[i] = jcout[i]; J.mode[i] = jmode[i];
    }
    J.wstart[9] = acc;
    const void* sv[18] = {s0a,b0a,s0b,b0b,sd0,bd0,s1a,b1a,s1b,b1b,sd1,bd1,s2a,b2a,s2b,b2b,s2c,b2c};
    for (int i = 0; i < 18; ++i) J.s[i] = sv[i];
    const u32 ptot = acc + 768;
    const int prep_blocks = (int)((ptot + 255) / 256);

    float *cs0a=S+0,  *cb0a=S+16,  *cs0b=S+32,  *cb0b=S+48;
    float *csd0=S+64, *cbd0=S+96,  *cs1a=S+128, *cb1a=S+160, *cs1b=S+192, *cb1b=S+224;
    float *csd1=S+256,*cbd1=S+320, *cs2a=S+384, *cb2a=S+448, *cs2b=S+512, *cb2b=S+576, *cs2c=S+640, *cb2c=S+704;

    // Pipeline byte-identical to round 6 (465 us). PROBE: +16 null dispatches at end.
    prepact_k<<<8192 + prep_blocks, 256, 0, stream>>>(J, FR, S, (const u16*)s0a, flag,
                                                      x, bmask, cnt, Xp);
    scatter2m_k<<<1664, 256, 0, stream>>>(Xp, bmask, idxmap, alist, Fb0, cnt, m1, m2);

    // stage A (128^3, 16ch, ~5% active)
    sconvm_k<<<2048, 256, 0, stream>>>(Fb0, idxmap, alist, cnt, wfs0a, cs0a, cb0a, Fb1);
    sconvm_k<<<2048, 256, 0, stream>>>(Fb1, idxmap, alist, cnt, wfs0b, cs0b, cb0b, Fb2);
    // down0 -> 64^3 x 32 bf16 NDHWC
    convd0m_k<<<4096, 256, 0, stream>>>(Fb2, idxmap, fd0, csd0, cbd0, m1, Rb1);
    // 64^3 stage — M=32/wave, 2x2-row LDS-staged (512-thread blocks, 64 KB LDS)
    mconvw_k<64,32,32,1,false,0><<<1024, 512, 0, stream>>>(Rb1, f1a, cs1a, cb1a, m1, Rb2, flag);
    mconvw_k<64,32,32,1,false,0><<<1024, 512, 0, stream>>>(Rb2, f1b, cs1b, cb1b, m1, Rb1, flag);
    // down1 -> 32^3 x 64 (stride 2, NSPLIT=2)
    mconv_k<64,32,32,64,2,2,false><<<1024, 256, 0, stream>>>(Rb1, fd1, csd1, cbd1, m2, Rb2, flag);
    // 32^3 stage — CSPLIT=2
    mconvw_k<32,64,64,2,false,0><<<256, 512, 0, stream>>>(Rb2, f2a, cs2a, cb2a, m2, Rb1, flag);
    mconvw_k<32,64,64,2,false,0><<<256, 512, 0, stream>>>(Rb1, f2b, cs2b, cb2b, m2, Rb2, flag);
    // final conv: NCDHW f32 (or bf16 per flag) to d_out
    mconvw_k<32,64,64,2,true,0><<<256, 512, 0, stream>>>(Rb2, f2c, cs2c, cb2c, m2, d_out, flag);

    // ---- dispatch-overhead probe: 16 empty kernels; dur_us = base + 16*OH ----
    for (int i = 0; i < 16; ++i){
        null_k<<<2048, 256, 0, stream>>>(flag);
    }
}

// Round 9
// 459.810 us; speedup vs baseline: 1.1389x; 1.0765x over previous
//
#include <hip/hip_runtime.h>
#include <cstdint>

typedef unsigned short u16;
typedef unsigned int u32;
typedef unsigned char u8;
typedef unsigned long long u64;
typedef __attribute__((ext_vector_type(8))) short short8;
typedef __attribute__((ext_vector_type(4))) float f32x4;

#define CAP 131072  // max compact slots at 128^3 (~105k expected active)

__device__ __forceinline__ float bf1(u16 v){ union{u32 i; float f;} c; c.i = ((u32)v) << 16; return c.f; }
__device__ __forceinline__ u16 f2bf(float f){
    union{float f; u32 i;} c; c.f = f; u32 i = c.i;
    return (u16)((i + 0x7FFFu + ((i >> 16) & 1u)) >> 16);   // RTNE
}
__device__ __forceinline__ u16 bits2bf(u32 b){ union{u32 i; float f;} c; c.i = b; return f2bf(c.f); }

struct PAll {
    const void* w[9];
    u32 wstart[10];
    int cin[9], cout[9], mode[9];   // 0=16x16 wfrag, 1=d0 pair(16->32), 2=subm0 pair(16->16)
    const void* s[18];
};

// ---- fused phase 0+1: blocks [0,8192) = active bitmask + packed features;
// blocks [8192,..) = weight-fragment + scale prep. Flag self-derived per thread. ----
__global__ __launch_bounds__(256)
void prepact_k(PAll J, u16* __restrict__ FR, float* __restrict__ S,
               const u16* __restrict__ s0a_probe, u32* __restrict__ flag,
               const void* __restrict__ xv, u64* __restrict__ bmask,
               u32* __restrict__ cnt, u16* __restrict__ Xp){
    int ok = 1;
    #pragma unroll
    for (int i = 0; i < 8; i += 2){
        u16 vv = s0a_probe[i];
        if (vv < 0x3F00u || vv > 0x3FC0u) ok = 0;
    }
    const u32 isbf = ok ? 1u : 0u;

    if (blockIdx.x < 8192){
        const int v = blockIdx.x * 256 + threadIdx.x;
        const size_t N = 2097152;
        u16 vals[16];
        u32 a = 0;
        if (isbf) {
            const u16* x = (const u16*)xv;
            #pragma unroll
            for (int c = 0; c < 16; ++c){
                const u16 b = x[(size_t)c * N + v];
                vals[c] = b;
                a |= (u32)b & 0x7FFFu;
            }
        } else {
            const u32* x = (const u32*)xv;
            #pragma unroll
            for (int c = 0; c < 16; ++c){
                const u32 b = x[(size_t)c * N + v];
                vals[c] = bits2bf(b);
                a |= b & 0x7FFFFFFFu;
            }
        }
        const bool act = (a != 0);
        const u64 m = __ballot(act);
        __shared__ u32 wc[4];
        const int lane = threadIdx.x & 63, wv = threadIdx.x >> 6;
        if (lane == 0) { bmask[v >> 6] = m; wc[wv] = (u32)__popcll(m); }
        __syncthreads();
        if (act){
            u32 wbase = 0;
            for (int i = 0; i < wv; ++i) wbase += wc[i];
            const u32 local = wbase + (u32)__popcll(m & ((1ull << lane) - 1ull));
            u16* dst = Xp + ((size_t)blockIdx.x * 256 + local) * 16;
            *(short8*)(dst)     = *(const short8*)(vals);
            *(short8*)(dst + 8) = *(const short8*)(vals + 8);
        }
        return;
    }

    const int gi = (int)(blockIdx.x - 8192) * 256 + threadIdx.x;
    if (gi == 0) { flag[0] = isbf; cnt[0] = 0; }

    const int wtot = (int)J.wstart[9];
    if (gi < wtot){
        int j = 0;
        while (gi >= (int)J.wstart[j + 1]) ++j;
        const int i = gi - (int)J.wstart[j];
        const void* w = J.w[j];
        const int CIN = J.cin[j], COUT = J.cout[j];
        const int jj = i & 7;
        const int lane = (i >> 3) & 63;
        int rest = i >> 9;
        int src = -1;
        if (J.mode[j] == 0){
            const int KC = CIN >> 5, NT = COUT >> 4;
            const int nt = rest % NT; rest /= NT;
            const int kc = rest % KC; const int tap = rest / KC;
            const int k = kc * 32 + (lane >> 4) * 8 + jj;
            const int co = nt * 16 + (lane & 15);
            src = (tap * CIN + k) * COUT + co;
        } else if (J.mode[j] == 1){
            const int nt = rest & 1; const int pair = rest >> 1;
            const int kg = (lane >> 4) * 8 + jj;
            const int tap = pair * 2 + (kg >> 4);
            const int ci = kg & 15;
            const int co = nt * 16 + (lane & 15);
            if (tap < 27) src = (tap * 16 + ci) * 32 + co;
        } else {
            const int pair = rest;
            const int kg = (lane >> 4) * 8 + jj;
            const int tap = pair * 2 + (kg >> 4);
            const int ci = kg & 15;
            const int co = lane & 15;
            if (tap < 27) src = (tap * 16 + ci) * 16 + co;
        }
        float v = 0.f;
        if (src >= 0) v = isbf ? bf1(((const u16*)w)[src]) : ((const float*)w)[src];
        FR[gi] = f2bf(v);
    } else {
        const int i2 = gi - wtot;
        const int len[18] = {16,16,16,16,32,32,32,32,32,32,64,64,64,64,64,64,64,64};
        const int off[18] = {0,16,32,48,64,96,128,160,192,224,256,320,384,448,512,576,640,704};
        if (i2 < 768){
            int b = 0, base = 0;
            while (i2 >= base + len[b]) { base += len[b]; ++b; }
            const int t = i2 - base;
            const float v = isbf ? bf1(((const u16*)J.s[b])[t]) : ((const float*)J.s[b])[t];
            S[off[b] + t] = v;
        }
    }
}

// ---- fused: scatter (16 tiles/block, ONE atomic per block) + m1 + m2 from bmask ----
// blocks [0,512): scatter; [512,1536): m1; [1536,1664): m2
__global__ __launch_bounds__(256)
void scatter2m_k(const u16* __restrict__ Xp, const u64* __restrict__ bmask,
                 int* __restrict__ idxmap, int* __restrict__ alist,
                 u16* __restrict__ f, u32* __restrict__ cnt,
                 u8* __restrict__ m1, u8* __restrict__ m2){
    if (blockIdx.x < 512){
        const int lane = threadIdx.x & 63, wv = threadIdx.x >> 6;
        __shared__ u32 wcnt[16][4];
        __shared__ u32 tileoff[16];
        __shared__ u32 sbase;
        const int tile0 = blockIdx.x * 16;

        #pragma unroll
        for (int i = 0; i < 16; ++i){
            if (lane == 0){
                const u64 m = bmask[(size_t)(tile0 + i) * 4 + wv];
                wcnt[i][wv] = (u32)__popcll(m);
            }
        }
        __syncthreads();
        if (threadIdx.x == 0){
            u32 s = 0;
            #pragma unroll
            for (int i = 0; i < 16; ++i){
                tileoff[i] = s;
                s += wcnt[i][0] + wcnt[i][1] + wcnt[i][2] + wcnt[i][3];
            }
            sbase = atomicAdd(cnt, s);
        }
        __syncthreads();
        const u32 b0 = sbase;
        #pragma unroll
        for (int i = 0; i < 16; ++i){
            const u64 m = bmask[(size_t)(tile0 + i) * 4 + wv];
            const bool act = (m >> lane) & 1ull;
            u32 wbase = 0;
            for (int k = 0; k < wv; ++k) wbase += wcnt[i][k];
            const u32 rank = (u32)__popcll(m & ((1ull << lane) - 1ull));
            const int v = (tile0 + i) * 256 + threadIdx.x;
            int slot = -1;
            if (act){
                const u32 sl = b0 + tileoff[i] + wbase + rank;
                if (sl < CAP){
                    slot = (int)sl;
                    alist[slot] = v;
                    const u16* src = Xp + ((size_t)(tile0 + i) * 256 + wbase + rank) * 16;
                    u16* dst = f + (size_t)slot * 16;
                    *(short8*)(dst)     = *(const short8*)(src);
                    *(short8*)(dst + 8) = *(const short8*)(src + 8);
                }
            }
            idxmap[v] = slot;
        }
    } else if (blockIdx.x < 1536){
        const int v = (int)(blockIdx.x - 512) * 256 + threadIdx.x;
        const int xo = v & 63, yo = (v >> 6) & 63, zo = v >> 12;
        u32 a = 0;
        #pragma unroll
        for (int kz = 0; kz < 3; ++kz){ const int iz = 2*zo + kz - 1; if ((unsigned)iz >= 128u) continue;
          #pragma unroll
          for (int ky = 0; ky < 3; ++ky){ const int iy = 2*yo + ky - 1; if ((unsigned)iy >= 128u) continue;
            #pragma unroll
            for (int kx = 0; kx < 3; ++kx){ const int ix = 2*xo + kx - 1; if ((unsigned)ix >= 128u) continue;
              const int vv = (iz * 128 + iy) * 128 + ix;
              a |= (u32)((bmask[vv >> 6] >> (vv & 63)) & 1ull);
        }}}
        m1[v] = (u8)a;
    } else {
        const int v = (int)(blockIdx.x - 1536) * 256 + threadIdx.x;
        const int xo = v & 31, yo = (v >> 5) & 31, zo = v >> 10;
        const int xlo = max(0, 4*xo - 3), xhi = min(127, 4*xo + 3);
        const int w0 = xlo >> 6, w1 = xhi >> 6;
        u32 a = 0;
        #pragma unroll
        for (int dz = -3; dz <= 3; ++dz){ const int iz = 4*zo + dz; if ((unsigned)iz >= 128u) continue;
          #pragma unroll
          for (int dy = -3; dy <= 3; ++dy){ const int iy = 4*yo + dy; if ((unsigned)iy >= 128u) continue;
            const int rowword = ((iz * 128 + iy) * 128) >> 6;
            if (w0 == w1){
                const u64 mw = bmask[rowword + w0];
                const int sh = xlo & 63, len = xhi - xlo + 1;
                if ((mw >> sh) & ((1ull << len) - 1ull)) a = 1;
            } else {
                const u64 lo = bmask[rowword + w0] >> (xlo & 63);
                const u64 hi = bmask[rowword + w1] & ((1ull << ((xhi & 63) + 1)) - 1ull);
                if (lo | hi) a = 1;
            }
        }}
        m2[v] = (u8)a;
    }
}

// ---- MFMA sparse subm conv at 128^3: compact bf16 16ch -> 16ch ----
// M=32/wave: two 16-slot halves, independent acc chains, shared B fragments.
__global__ __launch_bounds__(256)
void sconvm_k(const u16* __restrict__ fin, const int* __restrict__ idxmap,
              const int* __restrict__ alist, const u32* __restrict__ cnt,
              const u16* __restrict__ wf, const float* __restrict__ sc,
              const float* __restrict__ sh, u16* __restrict__ fout){
    const int n = min((int)cnt[0], CAP);
    const int j = blockIdx.x * 4 + (threadIdx.x >> 6);
    const int sbase = j * 32;
    if (sbase >= n) return;
    const int lane = threadIdx.x & 63;
    const int m = lane & 15, quad = lane >> 4;

    int sn0[14], sn1[14];
    #pragma unroll
    for (int h = 0; h < 2; ++h){
        const int s = sbase + h * 16 + m;
        const int v = (s < n) ? alist[s] : -1;
        int xo = 0, yo = 0, zo = 0;
        if (v >= 0){ xo = v & 127; yo = (v >> 7) & 127; zo = v >> 14; }
        int* sn = h ? sn1 : sn0;
        #pragma unroll
        for (int p = 0; p < 14; ++p){
            const int tp = p * 2 + (quad >> 1);
            int sv = -1;
            if (v >= 0 && tp < 27){
                const int kz = tp / 9, ky = (tp / 3) % 3, kx = tp % 3;
                const int iz = zo + kz - 1, iy = yo + ky - 1, ix = xo + kx - 1;
                if ((unsigned)iz < 128u && (unsigned)iy < 128u && (unsigned)ix < 128u){
                    sv = idxmap[((size_t)iz * 128 + iy) * 128 + ix];
                }
            }
            sn[p] = sv;
        }
    }

    f32x4 acc0 = {0.f,0.f,0.f,0.f}, acc1 = {0.f,0.f,0.f,0.f};
    #pragma unroll
    for (int p = 0; p < 14; ++p){
        short8 b = *(const short8*)(wf + ((size_t)p * 64 + lane) * 8);
        short8 a0 = {0,0,0,0,0,0,0,0};
        short8 a1 = {0,0,0,0,0,0,0,0};
        if (sn0[p] >= 0) a0 = *(const short8*)(fin + (size_t)sn0[p] * 16 + (quad & 1) * 8);
        if (sn1[p] >= 0) a1 = *(const short8*)(fin + (size_t)sn1[p] * 16 + (quad & 1) * 8);
        acc0 = __builtin_amdgcn_mfma_f32_16x16x32_bf16(a0, b, acc0, 0, 0, 0);
        acc1 = __builtin_amdgcn_mfma_f32_16x16x32_bf16(a1, b, acc1, 0, 0, 0);
    }

    const int co = lane & 15;
    const float scl = sc[co], shf = sh[co];
    #pragma unroll
    for (int r = 0; r < 4; ++r){
        const int srow0 = sbase + quad * 4 + r;
        const int srow1 = sbase + 16 + quad * 4 + r;
        if (srow0 < n) fout[(size_t)srow0 * 16 + co] = f2bf(fmaxf(acc0[r] * scl + shf, 0.f));
        if (srow1 < n) fout[(size_t)srow1 * 16 + co] = f2bf(fmaxf(acc1[r] * scl + shf, 0.f));
    }
}

// ---- down0 MFMA: compact bf16 16ch @128^3 -> bf16 NDHWC 32ch @64^3 ----
// M=32/wave: two 16-x halves, 4 independent acc chains, shared B fragments.
__global__ __launch_bounds__(256)
void convd0m_k(const u16* __restrict__ fbuf, const int* __restrict__ idxmap,
               const u16* __restrict__ wf, const float* __restrict__ sc,
               const float* __restrict__ sh, const u8* __restrict__ mk,
               u16* __restrict__ out)
{
    const int wj = blockIdx.x * 4 + (threadIdx.x >> 6);   // [0,8192): 2 xblk x 64 y x 64 z
    const int lane = threadIdx.x & 63;
    const int m = lane & 15, quad = lane >> 4;
    const int xo_b = (wj & 1) * 32;
    const int yo = (wj >> 1) & 63;
    const int zo = wj >> 7;
    const int ixA = (xo_b + m) * 2 - 1;
    const int ixB = (xo_b + 16 + m) * 2 - 1;

    int sn0[14], sn1[14];
    #pragma unroll
    for (int h = 0; h < 2; ++h){
        const int ix_m = h ? ixB : ixA;
        int* sn = h ? sn1 : sn0;
        #pragma unroll
        for (int p = 0; p < 14; ++p){
            const int tp = p * 2 + (quad >> 1);
            int sv = -1;
            if (tp < 27){
                const int kz = tp / 9, ky = (tp / 3) % 3, kx = tp % 3;
                const int iz = 2*zo + kz - 1, iy = 2*yo + ky - 1, ix = ix_m + kx;
                if ((unsigned)iz < 128u && (unsigned)iy < 128u && (unsigned)ix < 128u){
                    sv = idxmap[((size_t)iz * 128 + iy) * 128 + ix];
                }
            }
            sn[p] = sv;
        }
    }

    f32x4 accA0 = {0.f,0.f,0.f,0.f}, accA1 = {0.f,0.f,0.f,0.f};
    f32x4 accB0 = {0.f,0.f,0.f,0.f}, accB1 = {0.f,0.f,0.f,0.f};
    #pragma unroll
    for (int p = 0; p < 14; ++p){
        short8 b0 = *(const short8*)(wf + ((size_t)(p*2+0) * 64 + lane) * 8);
        short8 b1 = *(const short8*)(wf + ((size_t)(p*2+1) * 64 + lane) * 8);
        short8 aA = {0,0,0,0,0,0,0,0};
        short8 aB = {0,0,0,0,0,0,0,0};
        if (sn0[p] >= 0) aA = *(const short8*)(fbuf + (size_t)sn0[p] * 16 + (quad & 1) * 8);
        if (sn1[p] >= 0) aB = *(const short8*)(fbuf + (size_t)sn1[p] * 16 + (quad & 1) * 8);
        accA0 = __builtin_amdgcn_mfma_f32_16x16x32_bf16(aA, b0, accA0, 0, 0, 0);
        accA1 = __builtin_amdgcn_mfma_f32_16x16x32_bf16(aA, b1, accA1, 0, 0, 0);
        accB0 = __builtin_amdgcn_mfma_f32_16x16x32_bf16(aB, b0, accB0, 0, 0, 0);
        accB1 = __builtin_amdgcn_mfma_f32_16x16x32_bf16(aB, b1, accB1, 0, 0, 0);
    }

    const int baseVox = (zo * 64 + yo) * 64 + xo_b;
    const int vbA = baseVox + quad * 4;
    const int vbB = baseVox + 16 + quad * 4;
    const u32 m4A = *(const u32*)(mk + vbA);
    const u32 m4B = *(const u32*)(mk + vbB);
    const int n = lane & 15;
    #pragma unroll
    for (int nt = 0; nt < 2; ++nt){
        const int co = nt * 16 + n;
        const float s = sc[co], h = sh[co];
        const f32x4 aA = nt ? accA1 : accA0;
        const f32x4 aB = nt ? accB1 : accB0;
        #pragma unroll
        for (int r = 0; r < 4; ++r){
            float vA = fmaxf(aA[r] * s + h, 0.f);
            float vB = fmaxf(aB[r] * s + h, 0.f);
            vA = ((m4A >> (8*r)) & 0xFFu) ? vA : 0.f;
            vB = ((m4B >> (8*r)) & 0xFFu) ? vB : 0.f;
            out[(size_t)(vbA + r) * 32 + co] = f2bf(vA);
            out[(size_t)(vbB + r) * 32 + co] = f2bf(vB);
        }
    }
}

// ---- generic direct-global MFMA conv (down1); NSPLIT waves share one output tile's channels ----
template<int DIN, int DOUT, int CIN, int COUT, int STRIDE, int NSPLIT, bool FINAL>
__global__ __launch_bounds__(256)
void mconv_k(const u16* __restrict__ in, const u16* __restrict__ wf,
             const float* __restrict__ sc, const float* __restrict__ sh,
             const u8* __restrict__ mk, void* __restrict__ out,
             const u32* __restrict__ flag)
{
    constexpr int KC = CIN / 32;
    constexpr int NT = COUT / 16;
    constexpr int NTE = NT / NSPLIT;
    constexpr int XT = DOUT / 16;
    const int wjj = blockIdx.x * 4 + (threadIdx.x >> 6);
    const int cs = wjj % NSPLIT;
    const int wj = wjj / NSPLIT;
    const int lane = threadIdx.x & 63;
    const int m = lane & 15, quad = lane >> 4;

    const int xo_b = (wj % XT) * 16;
    const int yo = (wj / XT) % DOUT;
    const int zo = wj / (XT * DOUT);

    f32x4 acc[NTE];
    #pragma unroll
    for (int i = 0; i < NTE; ++i) acc[i] = (f32x4){0.f,0.f,0.f,0.f};

    const int ix0 = (xo_b + m) * STRIDE - 1;
    for (int kz = 0; kz < 3; ++kz){
      const int iz = zo * STRIDE + kz - 1;
      if ((unsigned)iz >= (unsigned)DIN) continue;
      for (int ky = 0; ky < 3; ++ky){
        const int iy = yo * STRIDE + ky - 1;
        if ((unsigned)iy >= (unsigned)DIN) continue;
        const size_t rowb = ((size_t)iz * DIN + iy) * DIN;
        #pragma unroll
        for (int kx = 0; kx < 3; ++kx){
          const int ix = ix0 + kx;
          const bool v = (unsigned)ix < (unsigned)DIN;
          const int tap = (kz*3 + ky)*3 + kx;
          const u16* ap = in + (rowb + ix) * CIN + quad * 8;
          const u16* bp = wf + (size_t)tap * KC * NT * 512 + lane * 8;
          #pragma unroll
          for (int kc = 0; kc < KC; ++kc){
            short8 a = {0,0,0,0,0,0,0,0};
            if (v) a = *(const short8*)(ap + kc * 32);
            #pragma unroll
            for (int nt = 0; nt < NTE; ++nt){
              short8 b = *(const short8*)(bp + (kc * NT + cs * NTE + nt) * 512);
              acc[nt] = __builtin_amdgcn_mfma_f32_16x16x32_bf16(a, b, acc[nt], 0, 0, 0);
            }
          }
    }}}

    const int vb = wj * 16 + quad * 4;
    const u32 m4 = *(const u32*)(mk + vb);
    const int n = lane & 15;
    #pragma unroll
    for (int nt = 0; nt < NTE; ++nt){
        const int co = (cs * NTE + nt) * 16 + n;
        const float s = sc[co], h = sh[co];
        #pragma unroll
        for (int r = 0; r < 4; ++r){
            float val = fmaxf(acc[nt][r] * s + h, 0.f);
            val = ((m4 >> (8*r)) & 0xFFu) ? val : 0.f;
            ((u16*)out)[(size_t)(vb + r) * COUT + co] = f2bf(val);
        }
    }
    (void)flag;
}

// ---- LDS-staged 16x16 MFMA conv, stride 1, 2x2 output rows per block, M=32/wave ----
template<int D, int CIN, int COUT, int CSPLIT, bool FINAL>
__global__ __launch_bounds__((D/32)*4*64*CSPLIT)
void mconvw_k(const u16* __restrict__ in, const u16* __restrict__ wf,
              const float* __restrict__ sc, const float* __restrict__ sh,
              const u8* __restrict__ mk, void* __restrict__ out,
              const u32* __restrict__ flag)
{
    constexpr int KC = CIN / 32;
    constexpr int NT = COUT / 16;
    constexpr int NTE = NT / CSPLIT;
    constexpr int CH8 = CIN / 8;
    constexpr int WPR = D / 32;
    constexpr int BT = WPR * 4 * 64 * CSPLIT;
    __shared__ u16 tile[16 * 2048];

    const int t = threadIdx.x;
    const int yp = blockIdx.x % (D / 2);
    const int zp = blockIdx.x / (D / 2);

    #pragma unroll
    for (int ri = 0; ri < 16; ++ri){
        const int dz = ri >> 2, jy = ri & 3;
        const int iz = 2*zp + dz - 1, iy = 2*yp + jy - 1;
        if ((unsigned)iz < (unsigned)D && (unsigned)iy < (unsigned)D){
            const u16* src = in + ((size_t)(iz * D + iy) * D) * CIN;
            u16* dst = &tile[ri * 2048];
            for (int c = t; c < D * CH8; c += BT){
                const int x = c / CH8, c8 = c % CH8;
                *(short8*)(dst + (c8 * D + x) * 8) = *(const short8*)(src + c * 8);
            }
        }
    }
    __syncthreads();

    const int lane = t & 63, w = t >> 6;
    const int cs = w % CSPLIT;
    const int w2 = w / CSPLIT;
    const int r = w2 / WPR;
    const int r2z = r >> 1, r2y = r & 1;
    const int xo_b = (w2 % WPR) * 32;
    const int zo = 2*zp + r2z, yo = 2*yp + r2y;
    const int m = lane & 15, quad = lane >> 4;

    f32x4 acc0[NTE], acc1[NTE];
    #pragma unroll
    for (int i = 0; i < NTE; ++i){ acc0[i] = (f32x4){0.f,0.f,0.f,0.f}; acc1[i] = (f32x4){0.f,0.f,0.f,0.f}; }

    #pragma unroll
    for (int kz = 0; kz < 3; ++kz){
      const int iz = zo + kz - 1;
      if ((unsigned)iz >= (unsigned)D) continue;
      #pragma unroll
      for (int ky = 0; ky < 3; ++ky){
        const int iy = yo + ky - 1;
        if ((unsigned)iy >= (unsigned)D) continue;
        const u16* row = &tile[((r2z + kz) * 4 + (r2y + ky)) * 2048];
        #pragma unroll
        for (int kx = 0; kx < 3; ++kx){
          const int ix0 = xo_b + m + kx - 1;
          const int ix1 = ix0 + 16;
          const bool aok0 = (unsigned)ix0 < (unsigned)D;
          const bool aok1 = (unsigned)ix1 < (unsigned)D;
          const int tap = (kz * 3 + ky) * 3 + kx;
          const u16* bp = wf + (size_t)tap * KC * NT * 512 + lane * 8;
          #pragma unroll
          for (int kc = 0; kc < KC; ++kc){
            short8 a0 = {0,0,0,0,0,0,0,0};
            short8 a1 = {0,0,0,0,0,0,0,0};
            if (aok0) a0 = *(const short8*)(row + ((kc * 4 + quad) * D + ix0) * 8);
            if (aok1) a1 = *(const short8*)(row + ((kc * 4 + quad) * D + ix1) * 8);
            #pragma unroll
            for (int nt = 0; nt < NTE; ++nt){
              short8 b = *(const short8*)(bp + (kc * NT + cs * NTE + nt) * 512);
              acc0[nt] = __builtin_amdgcn_mfma_f32_16x16x32_bf16(a0, b, acc0[nt], 0, 0, 0);
              acc1[nt] = __builtin_amdgcn_mfma_f32_16x16x32_bf16(a1, b, acc1[nt], 0, 0, 0);
            }
          }
        }
      }
    }

    const int base = (zo * D + yo) * D;
    const int vb0 = base + xo_b + quad * 4;
    const int vb1 = vb0 + 16;
    const u32 m4_0 = *(const u32*)(mk + vb0);
    const u32 m4_1 = *(const u32*)(mk + vb1);
    const int n = lane & 15;
    if (FINAL) {
        const bool bfout = flag[0] != 0;
        #pragma unroll
        for (int nt = 0; nt < NTE; ++nt){
            const int co = (cs * NTE + nt) * 16 + n;
            const float s = sc[co], h = sh[co];
            float4 o0, o1;
            float* p0 = &o0.x; float* p1 = &o1.x;
            #pragma unroll
            for (int r4 = 0; r4 < 4; ++r4){
                float v0 = fmaxf(acc0[nt][r4] * s + h, 0.f);
                float v1 = fmaxf(acc1[nt][r4] * s + h, 0.f);
                p0[r4] = ((m4_0 >> (8*r4)) & 0xFFu) ? v0 : 0.f;
                p1[r4] = ((m4_1 >> (8*r4)) & 0xFFu) ? v1 : 0.f;
            }
            if (!bfout) {
                *(float4*)((float*)out + (size_t)co * (D*D*D) + vb0) = o0;
                *(float4*)((float*)out + (size_t)co * (D*D*D) + vb1) = o1;
            } else {
                u16* ob0 = (u16*)out + (size_t)co * (D*D*D) + vb0;
                u16* ob1 = (u16*)out + (size_t)co * (D*D*D) + vb1;
                #pragma unroll
                for (int r4 = 0; r4 < 4; ++r4){ ob0[r4] = f2bf(p0[r4]); ob1[r4] = f2bf(p1[r4]); }
            }
        }
    } else {
        #pragma unroll
        for (int nt = 0; nt < NTE; ++nt){
            const int co = (cs * NTE + nt) * 16 + n;
            const float s = sc[co], h = sh[co];
            #pragma unroll
            for (int r4 = 0; r4 < 4; ++r4){
                float v0 = fmaxf(acc0[nt][r4] * s + h, 0.f);
                float v1 = fmaxf(acc1[nt][r4] * s + h, 0.f);
                v0 = ((m4_0 >> (8*r4)) & 0xFFu) ? v0 : 0.f;
                v1 = ((m4_1 >> (8*r4)) & 0xFFu) ? v1 : 0.f;
                ((u16*)out)[(size_t)(vb0 + r4) * COUT + co] = f2bf(v0);
                ((u16*)out)[(size_t)(vb1 + r4) * COUT + co] = f2bf(v1);
            }
        }
    }
}

extern "C" void kernel_launch(void* const* d_in, const int* in_sizes, int n_in,
                              void* d_out, int out_size, void* d_ws, size_t ws_size,
                              hipStream_t stream)
{
    (void)out_size; (void)ws_size;

    int wb = 2;
    for (int i = 1; i < n_in; ++i) { if (in_sizes[i] == 6912) { wb = i; break; } }

    const void* x = d_in[0];
    const void *w0a=d_in[wb+0],  *s0a=d_in[wb+1],  *b0a=d_in[wb+2];
    const void *w0b=d_in[wb+3],  *s0b=d_in[wb+4],  *b0b=d_in[wb+5];
    const void *wd0=d_in[wb+6],  *sd0=d_in[wb+7],  *bd0=d_in[wb+8];
    const void *w1a=d_in[wb+9],  *s1a=d_in[wb+10], *b1a=d_in[wb+11];
    const void *w1b=d_in[wb+12], *s1b=d_in[wb+13], *b1b=d_in[wb+14];
    const void *wd1=d_in[wb+15], *sd1=d_in[wb+16], *bd1=d_in[wb+17];
    const void *w2a=d_in[wb+18], *s2a=d_in[wb+19], *b2a=d_in[wb+20];
    const void *w2b=d_in[wb+21], *s2b=d_in[wb+22], *b2b=d_in[wb+23];
    const void *w2c=d_in[wb+24], *s2c=d_in[wb+25], *b2c=d_in[wb+26];

    // ---- workspace layout (~128 MiB of 512) ----
    char* ws = (char*)d_ws;
    int*   idxmap = (int*)(ws);                     //  8,388,608
    u16*   Fb0    = (u16*)(ws + 8388608);           //  4,194,304
    u16*   Fb1    = (u16*)(ws + 12582912);          //  4,194,304
    u16*   Fb2    = (u16*)(ws + 16777216);          //  4,194,304
    u16*   Rb1    = (u16*)(ws + 25165824);          // 16,777,216
    u16*   Rb2    = (u16*)(ws + 41943040);          // 16,777,216
    u8*    m1     = (u8*)(ws + 58720256);           //    262,144
    u8*    m2     = (u8*)(ws + 58982400);           //     32,768
    u32*   cnt    = (u32*)(ws + 59015168);          //        256
    int*   alist  = (int*)(ws + 59015424);          //    524,288
    u16*   FR     = (u16*)(ws + 59539712);          //    943,616
    float* S      = (float*)(ws + 60483328);        //      3,072
    u32*   flag   = (u32*)(ws + 60486400);          //        256
    u64*   bmask  = (u64*)(ws + 60486656);          //    262,144
    u16*   Xp     = (u16*)(ws + 67108864);          // 67,108,864 (block-packed features)

    u16* wfs0a = FR + 0;
    u16* wfs0b = FR + 7168;
    u16* fd0   = FR + 14336;
    u16* f1a   = FR + 28672;
    u16* f1b   = FR + 56320;
    u16* fd1   = FR + 83968;
    u16* f2a   = FR + 139264;
    u16* f2b   = FR + 249856;
    u16* f2c   = FR + 360448;

    PAll J;
    const void* jsrc[9] = {w0a, w0b, wd0, w1a, w1b, wd1, w2a, w2b, w2c};
    const u32 jlen[9]   = {7168,7168,14336,27648,27648,55296,110592,110592,110592};
    const int jcin[9]   = {16,16,16,32,32,32,64,64,64};
    const int jcout[9]  = {16,16,32,32,32,64,64,64,64};
    const int jmode[9]  = {2,2,1,0,0,0,0,0,0};
    u32 acc = 0;
    for (int i = 0; i < 9; ++i){
        J.w[i] = jsrc[i]; J.wstart[i] = acc; acc += jlen[i];
        J.cin[i] = jcin[i]; J.cout[i] = jcout[i]; J.mode[i] = jmode[i];
    }
    J.wstart[9] = acc;
    const void* sv[18] = {s0a,b0a,s0b,b0b,sd0,bd0,s1a,b1a,s1b,b1b,sd1,bd1,s2a,b2a,s2b,b2b,s2c,b2c};
    for (int i = 0; i < 18; ++i) J.s[i] = sv[i];
    const u32 ptot = acc + 768;
    const int prep_blocks = (int)((ptot + 255) / 256);

    float *cs0a=S+0,  *cb0a=S+16,  *cs0b=S+32,  *cb0b=S+48;
    float *csd0=S+64, *cbd0=S+96,  *cs1a=S+128, *cb1a=S+160, *cs1b=S+192, *cb1b=S+224;
    float *csd1=S+256,*cbd1=S+320, *cs2a=S+384, *cb2a=S+448, *cs2b=S+512, *cb2b=S+576, *cs2c=S+640, *cb2c=S+704;

    // 10 graph nodes: prep, scatter+masks, subm0 x2 (M=32/wave), down0 (M=32/wave),
    // 64^3 x2, down1, 32^3 x3
    prepact_k<<<8192 + prep_blocks, 256, 0, stream>>>(J, FR, S, (const u16*)s0a, flag,
                                                      x, bmask, cnt, Xp);
    scatter2m_k<<<1664, 256, 0, stream>>>(Xp, bmask, idxmap, alist, Fb0, cnt, m1, m2);

    // stage A (128^3, 16ch, ~5% active) — M=32/wave, 2 acc chains, shared B
    sconvm_k<<<1024, 256, 0, stream>>>(Fb0, idxmap, alist, cnt, wfs0a, cs0a, cb0a, Fb1);
    sconvm_k<<<1024, 256, 0, stream>>>(Fb1, idxmap, alist, cnt, wfs0b, cs0b, cb0b, Fb2);
    // down0 -> 64^3 x 32 bf16 NDHWC — M=32/wave, 4 acc chains, shared B
    convd0m_k<<<2048, 256, 0, stream>>>(Fb2, idxmap, fd0, csd0, cbd0, m1, Rb1);
    // 64^3 stage — M=32/wave, 2x2-row LDS-staged (512-thread blocks, 64 KB LDS)
    mconvw_k<64,32,32,1,false><<<1024, 512, 0, stream>>>(Rb1, f1a, cs1a, cb1a, m1, Rb2, flag);
    mconvw_k<64,32,32,1,false><<<1024, 512, 0, stream>>>(Rb2, f1b, cs1b, cb1b, m1, Rb1, flag);
    // down1 -> 32^3 x 64 (stride 2, NSPLIT=2)
    mconv_k<64,32,32,64,2,2,false><<<1024, 256, 0, stream>>>(Rb1, fd1, csd1, cbd1, m2, Rb2, flag);
    // 32^3 stage — CSPLIT=2
    mconvw_k<32,64,64,2,false><<<256, 512, 0, stream>>>(Rb2, f2a, cs2a, cb2a, m2, Rb1, flag);
    mconvw_k<32,64,64,2,false><<<256, 512, 0, stream>>>(Rb1, f2b, cs2b, cb2b, m2, Rb2, flag);
    // final conv: NCDHW f32 (or bf16 per flag) to d_out
    mconvw_k<32,64,64,2,true ><<<256, 512, 0, stream>>>(Rb2, f2c, cs2c, cb2c, m2, d_out, flag);
}

// Round 10
// 459.258 us; speedup vs baseline: 1.1403x; 1.0012x over previous
//
#include <hip/hip_runtime.h>
#include <cstdint>

typedef unsigned short u16;
typedef unsigned int u32;
typedef unsigned char u8;
typedef unsigned long long u64;
typedef __attribute__((ext_vector_type(8))) short short8;
typedef __attribute__((ext_vector_type(4))) float f32x4;
typedef __attribute__((ext_vector_type(4))) unsigned int u32x4;

#define CAP 131072  // max compact slots at 128^3 (~105k expected active)

__device__ __forceinline__ float bf1(u16 v){ union{u32 i; float f;} c; c.i = ((u32)v) << 16; return c.f; }
__device__ __forceinline__ u16 f2bf(float f){
    union{float f; u32 i;} c; c.f = f; u32 i = c.i;
    return (u16)((i + 0x7FFFu + ((i >> 16) & 1u)) >> 16);   // RTNE
}
__device__ __forceinline__ u16 bits2bf(u32 b){ union{u32 i; float f;} c; c.i = b; return f2bf(c.f); }

struct PAll {
    const void* w[9];
    u32 wstart[10];
    int cin[9], cout[9], mode[9];   // 0=16x16 wfrag, 1=d0 pair(16->32), 2=subm0 pair(16->16)
    const void* s[18];
};

// ---- fused phase 0+1: blocks [0,2048) = active bitmask + packed features (4 voxels/thread,
// 16B/lane vectorized x reads); blocks [2048,..) = weight-fragment + scale prep. ----
__global__ __launch_bounds__(256)
void prepact_k(PAll J, u16* __restrict__ FR, float* __restrict__ S,
               const u16* __restrict__ s0a_probe, u32* __restrict__ flag,
               const void* __restrict__ xv, u64* __restrict__ bmask,
               u32* __restrict__ cnt, u16* __restrict__ Xp){
    int ok = 1;
    #pragma unroll
    for (int i = 0; i < 8; i += 2){
        u16 vv = s0a_probe[i];
        if (vv < 0x3F00u || vv > 0x3FC0u) ok = 0;
    }
    const u32 isbf = ok ? 1u : 0u;

    if (blockIdx.x < 2048){
        const int t = threadIdx.x;
        const int v0 = (int)blockIdx.x * 1024 + t * 4;
        const size_t N = 2097152;
        u16 vals[4][16];            // [voxel j][channel c]
        u32 nib = 0;
        if (isbf){
            const u64* x = (const u64*)xv;
            #pragma unroll
            for (int c = 0; c < 16; ++c){
                const u64 q = x[((size_t)c * N + (size_t)v0) >> 2];
                const u16 b0 = (u16)q, b1 = (u16)(q >> 16), b2 = (u16)(q >> 32), b3 = (u16)(q >> 48);
                vals[0][c] = b0; vals[1][c] = b1; vals[2][c] = b2; vals[3][c] = b3;
                if (b0 & 0x7FFFu) nib |= 1u;
                if (b1 & 0x7FFFu) nib |= 2u;
                if (b2 & 0x7FFFu) nib |= 4u;
                if (b3 & 0x7FFFu) nib |= 8u;
            }
        } else {
            const u32x4* x = (const u32x4*)xv;
            #pragma unroll
            for (int c = 0; c < 16; ++c){
                const u32x4 q = x[((size_t)c * N + (size_t)v0) >> 2];
                #pragma unroll
                for (int j = 0; j < 4; ++j){
                    vals[j][c] = bits2bf(q[j]);
                    if (q[j] & 0x7FFFFFFFu) nib |= (1u << j);
                }
            }
        }

        __shared__ u8  nibs[256];
        __shared__ u64 words[16];
        __shared__ u32 wcs[16];
        __shared__ u32 woff[16];
        nibs[t] = (u8)nib;
        __syncthreads();
        if (t < 16){
            u64 word = 0;
            #pragma unroll
            for (int i = 0; i < 16; ++i) word |= (u64)nibs[t * 16 + i] << (4 * i);
            words[t] = word;
            wcs[t] = (u32)__popcll(word);
            bmask[(size_t)blockIdx.x * 16 + t] = word;
        }
        __syncthreads();
        if (t < 16){
            const int T = t >> 2;           // 256-voxel tile of this word
            u32 s = 0;
            for (int w = T * 4; w < t; ++w) s += wcs[w];
            woff[t] = s;
        }
        __syncthreads();

        if (nib){
            const int w = t >> 4;           // word index 0..15
            const int T = t >> 6;           // tile index 0..3
            const int bpos = (t & 15) * 4;
            const u64 word = words[w];
            u32 loc = woff[w] + (u32)__popcll(word & ((1ull << bpos) - 1ull));
            const size_t tbase = ((size_t)blockIdx.x * 4 + T) * 256;
            #pragma unroll
            for (int j = 0; j < 4; ++j){
                if (nib & (1u << j)){
                    u16* dst = Xp + (tbase + loc) * 16;
                    short8 lo, hi;
                    lo[0]=(short)vals[j][0]; lo[1]=(short)vals[j][1]; lo[2]=(short)vals[j][2]; lo[3]=(short)vals[j][3];
                    lo[4]=(short)vals[j][4]; lo[5]=(short)vals[j][5]; lo[6]=(short)vals[j][6]; lo[7]=(short)vals[j][7];
                    hi[0]=(short)vals[j][8]; hi[1]=(short)vals[j][9]; hi[2]=(short)vals[j][10]; hi[3]=(short)vals[j][11];
                    hi[4]=(short)vals[j][12]; hi[5]=(short)vals[j][13]; hi[6]=(short)vals[j][14]; hi[7]=(short)vals[j][15];
                    *(short8*)(dst)     = lo;
                    *(short8*)(dst + 8) = hi;
                    ++loc;
                }
            }
        }
        return;
    }

    const int gi = (int)(blockIdx.x - 2048) * 256 + threadIdx.x;
    if (gi == 0) { flag[0] = isbf; cnt[0] = 0; }

    const int wtot = (int)J.wstart[9];
    if (gi < wtot){
        int j = 0;
        while (gi >= (int)J.wstart[j + 1]) ++j;
        const int i = gi - (int)J.wstart[j];
        const void* w = J.w[j];
        const int CIN = J.cin[j], COUT = J.cout[j];
        const int jj = i & 7;
        const int lane = (i >> 3) & 63;
        int rest = i >> 9;
        int src = -1;
        if (J.mode[j] == 0){
            const int KC = CIN >> 5, NT = COUT >> 4;
            const int nt = rest % NT; rest /= NT;
            const int kc = rest % KC; const int tap = rest / KC;
            const int k = kc * 32 + (lane >> 4) * 8 + jj;
            const int co = nt * 16 + (lane & 15);
            src = (tap * CIN + k) * COUT + co;
        } else if (J.mode[j] == 1){
            const int nt = rest & 1; const int pair = rest >> 1;
            const int kg = (lane >> 4) * 8 + jj;
            const int tap = pair * 2 + (kg >> 4);
            const int ci = kg & 15;
            const int co = nt * 16 + (lane & 15);
            if (tap < 27) src = (tap * 16 + ci) * 32 + co;
        } else {
            const int pair = rest;
            const int kg = (lane >> 4) * 8 + jj;
            const int tap = pair * 2 + (kg >> 4);
            const int ci = kg & 15;
            const int co = lane & 15;
            if (tap < 27) src = (tap * 16 + ci) * 16 + co;
        }
        float v = 0.f;
        if (src >= 0) v = isbf ? bf1(((const u16*)w)[src]) : ((const float*)w)[src];
        FR[gi] = f2bf(v);
    } else {
        const int i2 = gi - wtot;
        const int len[18] = {16,16,16,16,32,32,32,32,32,32,64,64,64,64,64,64,64,64};
        const int off[18] = {0,16,32,48,64,96,128,160,192,224,256,320,384,448,512,576,640,704};
        if (i2 < 768){
            int b = 0, base = 0;
            while (i2 >= base + len[b]) { base += len[b]; ++b; }
            const int t = i2 - base;
            const float v = isbf ? bf1(((const u16*)J.s[b])[t]) : ((const float*)J.s[b])[t];
            S[off[b] + t] = v;
        }
    }
}

// ---- fused: scatter (16 tiles/block, ONE atomic per block) + m1 + m2 from bmask ----
// blocks [0,512): scatter; [512,1536): m1; [1536,1664): m2
__global__ __launch_bounds__(256)
void scatter2m_k(const u16* __restrict__ Xp, const u64* __restrict__ bmask,
                 int* __restrict__ idxmap, int* __restrict__ alist,
                 u16* __restrict__ f, u32* __restrict__ cnt,
                 u8* __restrict__ m1, u8* __restrict__ m2){
    if (blockIdx.x < 512){
        const int lane = threadIdx.x & 63, wv = threadIdx.x >> 6;
        __shared__ u32 wcnt[16][4];
        __shared__ u32 tileoff[16];
        __shared__ u32 sbase;
        const int tile0 = blockIdx.x * 16;

        #pragma unroll
        for (int i = 0; i < 16; ++i){
            if (lane == 0){
                const u64 m = bmask[(size_t)(tile0 + i) * 4 + wv];
                wcnt[i][wv] = (u32)__popcll(m);
            }
        }
        __syncthreads();
        if (threadIdx.x == 0){
            u32 s = 0;
            #pragma unroll
            for (int i = 0; i < 16; ++i){
                tileoff[i] = s;
                s += wcnt[i][0] + wcnt[i][1] + wcnt[i][2] + wcnt[i][3];
            }
            sbase = atomicAdd(cnt, s);
        }
        __syncthreads();
        const u32 b0 = sbase;
        #pragma unroll
        for (int i = 0; i < 16; ++i){
            const u64 m = bmask[(size_t)(tile0 + i) * 4 + wv];
            const bool act = (m >> lane) & 1ull;
            u32 wbase = 0;
            for (int k = 0; k < wv; ++k) wbase += wcnt[i][k];
            const u32 rank = (u32)__popcll(m & ((1ull << lane) - 1ull));
            const int v = (tile0 + i) * 256 + threadIdx.x;
            int slot = -1;
            if (act){
                const u32 sl = b0 + tileoff[i] + wbase + rank;
                if (sl < CAP){
                    slot = (int)sl;
                    alist[slot] = v;
                    const u16* src = Xp + ((size_t)(tile0 + i) * 256 + wbase + rank) * 16;
                    u16* dst = f + (size_t)slot * 16;
                    *(short8*)(dst)     = *(const short8*)(src);
                    *(short8*)(dst + 8) = *(const short8*)(src + 8);
                }
            }
            idxmap[v] = slot;
        }
    } else if (blockIdx.x < 1536){
        const int v = (int)(blockIdx.x - 512) * 256 + threadIdx.x;
        const int xo = v & 63, yo = (v >> 6) & 63, zo = v >> 12;
        u32 a = 0;
        #pragma unroll
        for (int kz = 0; kz < 3; ++kz){ const int iz = 2*zo + kz - 1; if ((unsigned)iz >= 128u) continue;
          #pragma unroll
          for (int ky = 0; ky < 3; ++ky){ const int iy = 2*yo + ky - 1; if ((unsigned)iy >= 128u) continue;
            #pragma unroll
            for (int kx = 0; kx < 3; ++kx){ const int ix = 2*xo + kx - 1; if ((unsigned)ix >= 128u) continue;
              const int vv = (iz * 128 + iy) * 128 + ix;
              a |= (u32)((bmask[vv >> 6] >> (vv & 63)) & 1ull);
        }}}
        m1[v] = (u8)a;
    } else {
        const int v = (int)(blockIdx.x - 1536) * 256 + threadIdx.x;
        const int xo = v & 31, yo = (v >> 5) & 31, zo = v >> 10;
        const int xlo = max(0, 4*xo - 3), xhi = min(127, 4*xo + 3);
        const int w0 = xlo >> 6, w1 = xhi >> 6;
        u32 a = 0;
        #pragma unroll
        for (int dz = -3; dz <= 3; ++dz){ const int iz = 4*zo + dz; if ((unsigned)iz >= 128u) continue;
          #pragma unroll
          for (int dy = -3; dy <= 3; ++dy){ const int iy = 4*yo + dy; if ((unsigned)iy >= 128u) continue;
            const int rowword = ((iz * 128 + iy) * 128) >> 6;
            if (w0 == w1){
                const u64 mw = bmask[rowword + w0];
                const int sh = xlo & 63, len = xhi - xlo + 1;
                if ((mw >> sh) & ((1ull << len) - 1ull)) a = 1;
            } else {
                const u64 lo = bmask[rowword + w0] >> (xlo & 63);
                const u64 hi = bmask[rowword + w1] & ((1ull << ((xhi & 63) + 1)) - 1ull);
                if (lo | hi) a = 1;
            }
        }}
        m2[v] = (u8)a;
    }
}

// ---- MFMA sparse subm conv at 128^3: compact bf16 16ch -> 16ch ----
// M=32/wave: two 16-slot halves, independent acc chains, shared B fragments.
__global__ __launch_bounds__(256)
void sconvm_k(const u16* __restrict__ fin, const int* __restrict__ idxmap,
              const int* __restrict__ alist, const u32* __restrict__ cnt,
              const u16* __restrict__ wf, const float* __restrict__ sc,
              const float* __restrict__ sh, u16* __restrict__ fout){
    const int n = min((int)cnt[0], CAP);
    const int j = blockIdx.x * 4 + (threadIdx.x >> 6);
    const int sbase = j * 32;
    if (sbase >= n) return;
    const int lane = threadIdx.x & 63;
    const int m = lane & 15, quad = lane >> 4;

    int sn0[14], sn1[14];
    #pragma unroll
    for (int h = 0; h < 2; ++h){
        const int s = sbase + h * 16 + m;
        const int v = (s < n) ? alist[s] : -1;
        int xo = 0, yo = 0, zo = 0;
        if (v >= 0){ xo = v & 127; yo = (v >> 7) & 127; zo = v >> 14; }
        int* sn = h ? sn1 : sn0;
        #pragma unroll
        for (int p = 0; p < 14; ++p){
            const int tp = p * 2 + (quad >> 1);
            int sv = -1;
            if (v >= 0 && tp < 27){
                const int kz = tp / 9, ky = (tp / 3) % 3, kx = tp % 3;
                const int iz = zo + kz - 1, iy = yo + ky - 1, ix = xo + kx - 1;
                if ((unsigned)iz < 128u && (unsigned)iy < 128u && (unsigned)ix < 128u){
                    sv = idxmap[((size_t)iz * 128 + iy) * 128 + ix];
                }
            }
            sn[p] = sv;
        }
    }

    f32x4 acc0 = {0.f,0.f,0.f,0.f}, acc1 = {0.f,0.f,0.f,0.f};
    #pragma unroll
    for (int p = 0; p < 14; ++p){
        short8 b = *(const short8*)(wf + ((size_t)p * 64 + lane) * 8);
        short8 a0 = {0,0,0,0,0,0,0,0};
        short8 a1 = {0,0,0,0,0,0,0,0};
        if (sn0[p] >= 0) a0 = *(const short8*)(fin + (size_t)sn0[p] * 16 + (quad & 1) * 8);
        if (sn1[p] >= 0) a1 = *(const short8*)(fin + (size_t)sn1[p] * 16 + (quad & 1) * 8);
        acc0 = __builtin_amdgcn_mfma_f32_16x16x32_bf16(a0, b, acc0, 0, 0, 0);
        acc1 = __builtin_amdgcn_mfma_f32_16x16x32_bf16(a1, b, acc1, 0, 0, 0);
    }

    const int co = lane & 15;
    const float scl = sc[co], shf = sh[co];
    #pragma unroll
    for (int r = 0; r < 4; ++r){
        const int srow0 = sbase + quad * 4 + r;
        const int srow1 = sbase + 16 + quad * 4 + r;
        if (srow0 < n) fout[(size_t)srow0 * 16 + co] = f2bf(fmaxf(acc0[r] * scl + shf, 0.f));
        if (srow1 < n) fout[(size_t)srow1 * 16 + co] = f2bf(fmaxf(acc1[r] * scl + shf, 0.f));
    }
}

// ---- down0 MFMA: compact bf16 16ch @128^3 -> bf16 NDHWC 32ch @64^3 ----
// M=32/wave: two 16-x halves, 4 independent acc chains, shared B fragments.
__global__ __launch_bounds__(256)
void convd0m_k(const u16* __restrict__ fbuf, const int* __restrict__ idxmap,
               const u16* __restrict__ wf, const float* __restrict__ sc,
               const float* __restrict__ sh, const u8* __restrict__ mk,
               u16* __restrict__ out)
{
    const int wj = blockIdx.x * 4 + (threadIdx.x >> 6);   // [0,8192): 2 xblk x 64 y x 64 z
    const int lane = threadIdx.x & 63;
    const int m = lane & 15, quad = lane >> 4;
    const int xo_b = (wj & 1) * 32;
    const int yo = (wj >> 1) & 63;
    const int zo = wj >> 7;
    const int ixA = (xo_b + m) * 2 - 1;
    const int ixB = (xo_b + 16 + m) * 2 - 1;

    int sn0[14], sn1[14];
    #pragma unroll
    for (int h = 0; h < 2; ++h){
        const int ix_m = h ? ixB : ixA;
        int* sn = h ? sn1 : sn0;
        #pragma unroll
        for (int p = 0; p < 14; ++p){
            const int tp = p * 2 + (quad >> 1);
            int sv = -1;
            if (tp < 27){
                const int kz = tp / 9, ky = (tp / 3) % 3, kx = tp % 3;
                const int iz = 2*zo + kz - 1, iy = 2*yo + ky - 1, ix = ix_m + kx;
                if ((unsigned)iz < 128u && (unsigned)iy < 128u && (unsigned)ix < 128u){
                    sv = idxmap[((size_t)iz * 128 + iy) * 128 + ix];
                }
            }
            sn[p] = sv;
        }
    }

    f32x4 accA0 = {0.f,0.f,0.f,0.f}, accA1 = {0.f,0.f,0.f,0.f};
    f32x4 accB0 = {0.f,0.f,0.f,0.f}, accB1 = {0.f,0.f,0.f,0.f};
    #pragma unroll
    for (int p = 0; p < 14; ++p){
        short8 b0 = *(const short8*)(wf + ((size_t)(p*2+0) * 64 + lane) * 8);
        short8 b1 = *(const short8*)(wf + ((size_t)(p*2+1) * 64 + lane) * 8);
        short8 aA = {0,0,0,0,0,0,0,0};
        short8 aB = {0,0,0,0,0,0,0,0};
        if (sn0[p] >= 0) aA = *(const short8*)(fbuf + (size_t)sn0[p] * 16 + (quad & 1) * 8);
        if (sn1[p] >= 0) aB = *(const short8*)(fbuf + (size_t)sn1[p] * 16 + (quad & 1) * 8);
        accA0 = __builtin_amdgcn_mfma_f32_16x16x32_bf16(aA, b0, accA0, 0, 0, 0);
        accA1 = __builtin_amdgcn_mfma_f32_16x16x32_bf16(aA, b1, accA1, 0, 0, 0);
        accB0 = __builtin_amdgcn_mfma_f32_16x16x32_bf16(aB, b0, accB0, 0, 0, 0);
        accB1 = __builtin_amdgcn_mfma_f32_16x16x32_bf16(aB, b1, accB1, 0, 0, 0);
    }

    const int baseVox = (zo * 64 + yo) * 64 + xo_b;
    const int vbA = baseVox + quad * 4;
    const int vbB = baseVox + 16 + quad * 4;
    const u32 m4A = *(const u32*)(mk + vbA);
    const u32 m4B = *(const u32*)(mk + vbB);
    const int n = lane & 15;
    #pragma unroll
    for (int nt = 0; nt < 2; ++nt){
        const int co = nt * 16 + n;
        const float s = sc[co], h = sh[co];
        const f32x4 aA = nt ? accA1 : accA0;
        const f32x4 aB = nt ? accB1 : accB0;
        #pragma unroll
        for (int r = 0; r < 4; ++r){
            float vA = fmaxf(aA[r] * s + h, 0.f);
            float vB = fmaxf(aB[r] * s + h, 0.f);
            vA = ((m4A >> (8*r)) & 0xFFu) ? vA : 0.f;
            vB = ((m4B >> (8*r)) & 0xFFu) ? vB : 0.f;
            out[(size_t)(vbA + r) * 32 + co] = f2bf(vA);
            out[(size_t)(vbB + r) * 32 + co] = f2bf(vB);
        }
    }
}

// ---- generic direct-global MFMA conv (down1); NSPLIT waves share one output tile's channels ----
template<int DIN, int DOUT, int CIN, int COUT, int STRIDE, int NSPLIT, bool FINAL>
__global__ __launch_bounds__(256)
void mconv_k(const u16* __restrict__ in, const u16* __restrict__ wf,
             const float* __restrict__ sc, const float* __restrict__ sh,
             const u8* __restrict__ mk, void* __restrict__ out,
             const u32* __restrict__ flag)
{
    constexpr int KC = CIN / 32;
    constexpr int NT = COUT / 16;
    constexpr int NTE = NT / NSPLIT;
    constexpr int XT = DOUT / 16;
    const int wjj = blockIdx.x * 4 + (threadIdx.x >> 6);
    const int cs = wjj % NSPLIT;
    const int wj = wjj / NSPLIT;
    const int lane = threadIdx.x & 63;
    const int m = lane & 15, quad = lane >> 4;

    const int xo_b = (wj % XT) * 16;
    const int yo = (wj / XT) % DOUT;
    const int zo = wj / (XT * DOUT);

    f32x4 acc[NTE];
    #pragma unroll
    for (int i = 0; i < NTE; ++i) acc[i] = (f32x4){0.f,0.f,0.f,0.f};

    const int ix0 = (xo_b + m) * STRIDE - 1;
    for (int kz = 0; kz < 3; ++kz){
      const int iz = zo * STRIDE + kz - 1;
      if ((unsigned)iz >= (unsigned)DIN) continue;
      for (int ky = 0; ky < 3; ++ky){
        const int iy = yo * STRIDE + ky - 1;
        if ((unsigned)iy >= (unsigned)DIN) continue;
        const size_t rowb = ((size_t)iz * DIN + iy) * DIN;
        #pragma unroll
        for (int kx = 0; kx < 3; ++kx){
          const int ix = ix0 + kx;
          const bool v = (unsigned)ix < (unsigned)DIN;
          const int tap = (kz*3 + ky)*3 + kx;
          const u16* ap = in + (rowb + ix) * CIN + quad * 8;
          const u16* bp = wf + (size_t)tap * KC * NT * 512 + lane * 8;
          #pragma unroll
          for (int kc = 0; kc < KC; ++kc){
            short8 a = {0,0,0,0,0,0,0,0};
            if (v) a = *(const short8*)(ap + kc * 32);
            #pragma unroll
            for (int nt = 0; nt < NTE; ++nt){
              short8 b = *(const short8*)(bp + (kc * NT + cs * NTE + nt) * 512);
              acc[nt] = __builtin_amdgcn_mfma_f32_16x16x32_bf16(a, b, acc[nt], 0, 0, 0);
            }
          }
    }}}

    const int vb = wj * 16 + quad * 4;
    const u32 m4 = *(const u32*)(mk + vb);
    const int n = lane & 15;
    #pragma unroll
    for (int nt = 0; nt < NTE; ++nt){
        const int co = (cs * NTE + nt) * 16 + n;
        const float s = sc[co], h = sh[co];
        #pragma unroll
        for (int r = 0; r < 4; ++r){
            float val = fmaxf(acc[nt][r] * s + h, 0.f);
            val = ((m4 >> (8*r)) & 0xFFu) ? val : 0.f;
            ((u16*)out)[(size_t)(vb + r) * COUT + co] = f2bf(val);
        }
    }
    (void)flag;
}

// ---- LDS-staged 16x16 MFMA conv, stride 1, 2x2 output rows per block, M=32/wave ----
template<int D, int CIN, int COUT, int CSPLIT, bool FINAL>
__global__ __launch_bounds__((D/32)*4*64*CSPLIT)
void mconvw_k(const u16* __restrict__ in, const u16* __restrict__ wf,
              const float* __restrict__ sc, const float* __restrict__ sh,
              const u8* __restrict__ mk, void* __restrict__ out,
              const u32* __restrict__ flag)
{
    constexpr int KC = CIN / 32;
    constexpr int NT = COUT / 16;
    constexpr int NTE = NT / CSPLIT;
    constexpr int CH8 = CIN / 8;
    constexpr int WPR = D / 32;
    constexpr int BT = WPR * 4 * 64 * CSPLIT;
    __shared__ u16 tile[16 * 2048];

    const int t = threadIdx.x;
    const int yp = blockIdx.x % (D / 2);
    const int zp = blockIdx.x / (D / 2);

    #pragma unroll
    for (int ri = 0; ri < 16; ++ri){
        const int dz = ri >> 2, jy = ri & 3;
        const int iz = 2*zp + dz - 1, iy = 2*yp + jy - 1;
        if ((unsigned)iz < (unsigned)D && (unsigned)iy < (unsigned)D){
            const u16* src = in + ((size_t)(iz * D + iy) * D) * CIN;
            u16* dst = &tile[ri * 2048];
            for (int c = t; c < D * CH8; c += BT){
                const int x = c / CH8, c8 = c % CH8;
                *(short8*)(dst + (c8 * D + x) * 8) = *(const short8*)(src + c * 8);
            }
        }
    }
    __syncthreads();

    const int lane = t & 63, w = t >> 6;
    const int cs = w % CSPLIT;
    const int w2 = w / CSPLIT;
    const int r = w2 / WPR;
    const int r2z = r >> 1, r2y = r & 1;
    const int xo_b = (w2 % WPR) * 32;
    const int zo = 2*zp + r2z, yo = 2*yp + r2y;
    const int m = lane & 15, quad = lane >> 4;

    f32x4 acc0[NTE], acc1[NTE];
    #pragma unroll
    for (int i = 0; i < NTE; ++i){ acc0[i] = (f32x4){0.f,0.f,0.f,0.f}; acc1[i] = (f32x4){0.f,0.f,0.f,0.f}; }

    #pragma unroll
    for (int kz = 0; kz < 3; ++kz){
      const int iz = zo + kz - 1;
      if ((unsigned)iz >= (unsigned)D) continue;
      #pragma unroll
      for (int ky = 0; ky < 3; ++ky){
        const int iy = yo + ky - 1;
        if ((unsigned)iy >= (unsigned)D) continue;
        const u16* row = &tile[((r2z + kz) * 4 + (r2y + ky)) * 2048];
        #pragma unroll
        for (int kx = 0; kx < 3; ++kx){
          const int ix0 = xo_b + m + kx - 1;
          const int ix1 = ix0 + 16;
          const bool aok0 = (unsigned)ix0 < (unsigned)D;
          const bool aok1 = (unsigned)ix1 < (unsigned)D;
          const int tap = (kz * 3 + ky) * 3 + kx;
          const u16* bp = wf + (size_t)tap * KC * NT * 512 + lane * 8;
          #pragma unroll
          for (int kc = 0; kc < KC; ++kc){
            short8 a0 = {0,0,0,0,0,0,0,0};
            short8 a1 = {0,0,0,0,0,0,0,0};
            if (aok0) a0 = *(const short8*)(row + ((kc * 4 + quad) * D + ix0) * 8);
            if (aok1) a1 = *(const short8*)(row + ((kc * 4 + quad) * D + ix1) * 8);
            #pragma unroll
            for (int nt = 0; nt < NTE; ++nt){
              short8 b = *(const short8*)(bp + (kc * NT + cs * NTE + nt) * 512);
              acc0[nt] = __builtin_amdgcn_mfma_f32_16x16x32_bf16(a0, b, acc0[nt], 0, 0, 0);
              acc1[nt] = __builtin_amdgcn_mfma_f32_16x16x32_bf16(a1, b, acc1[nt], 0, 0, 0);
            }
          }
        }
      }
    }

    const int base = (zo * D + yo) * D;
    const int vb0 = base + xo_b + quad * 4;
    const int vb1 = vb0 + 16;
    const u32 m4_0 = *(const u32*)(mk + vb0);
    const u32 m4_1 = *(const u32*)(mk + vb1);
    const int n = lane & 15;
    if (FINAL) {
        const bool bfout = flag[0] != 0;
        #pragma unroll
        for (int nt = 0; nt < NTE; ++nt){
            const int co = (cs * NTE + nt) * 16 + n;
            const float s = sc[co], h = sh[co];
            float4 o0, o1;
            float* p0 = &o0.x; float* p1 = &o1.x;
            #pragma unroll
            for (int r4 = 0; r4 < 4; ++r4){
                float v0 = fmaxf(acc0[nt][r4] * s + h, 0.f);
                float v1 = fmaxf(acc1[nt][r4] * s + h, 0.f);
                p0[r4] = ((m4_0 >> (8*r4)) & 0xFFu) ? v0 : 0.f;
                p1[r4] = ((m4_1 >> (8*r4)) & 0xFFu) ? v1 : 0.f;
            }
            if (!bfout) {
                *(float4*)((float*)out + (size_t)co * (D*D*D) + vb0) = o0;
                *(float4*)((float*)out + (size_t)co * (D*D*D) + vb1) = o1;
            } else {
                u16* ob0 = (u16*)out + (size_t)co * (D*D*D) + vb0;
                u16* ob1 = (u16*)out + (size_t)co * (D*D*D) + vb1;
                #pragma unroll
                for (int r4 = 0; r4 < 4; ++r4){ ob0[r4] = f2bf(p0[r4]); ob1[r4] = f2bf(p1[r4]); }
            }
        }
    } else {
        #pragma unroll
        for (int nt = 0; nt < NTE; ++nt){
            const int co = (cs * NTE + nt) * 16 + n;
            const float s = sc[co], h = sh[co];
            #pragma unroll
            for (int r4 = 0; r4 < 4; ++r4){
                float v0 = fmaxf(acc0[nt][r4] * s + h, 0.f);
                float v1 = fmaxf(acc1[nt][r4] * s + h, 0.f);
                v0 = ((m4_0 >> (8*r4)) & 0xFFu) ? v0 : 0.f;
                v1 = ((m4_1 >> (8*r4)) & 0xFFu) ? v1 : 0.f;
                ((u16*)out)[(size_t)(vb0 + r4) * COUT + co] = f2bf(v0);
                ((u16*)out)[(size_t)(vb1 + r4) * COUT + co] = f2bf(v1);
            }
        }
    }
}

extern "C" void kernel_launch(void* const* d_in, const int* in_sizes, int n_in,
                              void* d_out, int out_size, void* d_ws, size_t ws_size,
                              hipStream_t stream)
{
    (void)out_size; (void)ws_size;

    int wb = 2;
    for (int i = 1; i < n_in; ++i) { if (in_sizes[i] == 6912) { wb = i; break; } }

    const void* x = d_in[0];
    const void *w0a=d_in[wb+0],  *s0a=d_in[wb+1],  *b0a=d_in[wb+2];
    const void *w0b=d_in[wb+3],  *s0b=d_in[wb+4],  *b0b=d_in[wb+5];
    const void *wd0=d_in[wb+6],  *sd0=d_in[wb+7],  *bd0=d_in[wb+8];
    const void *w1a=d_in[wb+9],  *s1a=d_in[wb+10], *b1a=d_in[wb+11];
    const void *w1b=d_in[wb+12], *s1b=d_in[wb+13], *b1b=d_in[wb+14];
    const void *wd1=d_in[wb+15], *sd1=d_in[wb+16], *bd1=d_in[wb+17];
    const void *w2a=d_in[wb+18], *s2a=d_in[wb+19], *b2a=d_in[wb+20];
    const void *w2b=d_in[wb+21], *s2b=d_in[wb+22], *b2b=d_in[wb+23];
    const void *w2c=d_in[wb+24], *s2c=d_in[wb+25], *b2c=d_in[wb+26];

    // ---- workspace layout (~128 MiB of 512) ----
    char* ws = (char*)d_ws;
    int*   idxmap = (int*)(ws);                     //  8,388,608
    u16*   Fb0    = (u16*)(ws + 8388608);           //  4,194,304
    u16*   Fb1    = (u16*)(ws + 12582912);          //  4,194,304
    u16*   Fb2    = (u16*)(ws + 16777216);          //  4,194,304
    u16*   Rb1    = (u16*)(ws + 25165824);          // 16,777,216
    u16*   Rb2    = (u16*)(ws + 41943040);          // 16,777,216
    u8*    m1     = (u8*)(ws + 58720256);           //    262,144
    u8*    m2     = (u8*)(ws + 58982400);           //     32,768
    u32*   cnt    = (u32*)(ws + 59015168);          //        256
    int*   alist  = (int*)(ws + 59015424);          //    524,288
    u16*   FR     = (u16*)(ws + 59539712);          //    943,616
    float* S      = (float*)(ws + 60483328);        //      3,072
    u32*   flag   = (u32*)(ws + 60486400);          //        256
    u64*   bmask  = (u64*)(ws + 60486656);          //    262,144
    u16*   Xp     = (u16*)(ws + 67108864);          // 67,108,864 (block-packed features)

    u16* wfs0a = FR + 0;
    u16* wfs0b = FR + 7168;
    u16* fd0   = FR + 14336;
    u16* f1a   = FR + 28672;
    u16* f1b   = FR + 56320;
    u16* fd1   = FR + 83968;
    u16* f2a   = FR + 139264;
    u16* f2b   = FR + 249856;
    u16* f2c   = FR + 360448;

    PAll J;
    const void* jsrc[9] = {w0a, w0b, wd0, w1a, w1b, wd1, w2a, w2b, w2c};
    const u32 jlen[9]   = {7168,7168,14336,27648,27648,55296,110592,110592,110592};
    const int jcin[9]   = {16,16,16,32,32,32,64,64,64};
    const int jcout[9]  = {16,16,32,32,32,64,64,64,64};
    const int jmode[9]  = {2,2,1,0,0,0,0,0,0};
    u32 acc = 0;
    for (int i = 0; i < 9; ++i){
        J.w[i] = jsrc[i]; J.wstart[i] = acc; acc += jlen[i];
        J.cin[i] = jcin[i]; J.cout[i] = jcout[i]; J.mode[i] = jmode[i];
    }
    J.wstart[9] = acc;
    const void* sv[18] = {s0a,b0a,s0b,b0b,sd0,bd0,s1a,b1a,s1b,b1b,sd1,bd1,s2a,b2a,s2b,b2b,s2c,b2c};
    for (int i = 0; i < 18; ++i) J.s[i] = sv[i];
    const u32 ptot = acc + 768;
    const int prep_blocks = (int)((ptot + 255) / 256);

    float *cs0a=S+0,  *cb0a=S+16,  *cs0b=S+32,  *cb0b=S+48;
    float *csd0=S+64, *cbd0=S+96,  *cs1a=S+128, *cb1a=S+160, *cs1b=S+192, *cb1b=S+224;
    float *csd1=S+256,*cbd1=S+320, *cs2a=S+384, *cb2a=S+448, *cs2b=S+512, *cb2b=S+576, *cs2c=S+640, *cb2c=S+704;

    // 10 graph nodes: prep (vectorized, 2048 voxel blocks), scatter+masks, subm0 x2,
    // down0, 64^3 x2, down1, 32^3 x3
    prepact_k<<<2048 + prep_blocks, 256, 0, stream>>>(J, FR, S, (const u16*)s0a, flag,
                                                      x, bmask, cnt, Xp);
    scatter2m_k<<<1664, 256, 0, stream>>>(Xp, bmask, idxmap, alist, Fb0, cnt, m1, m2);

    // stage A (128^3, 16ch, ~5% active) — M=32/wave, 2 acc chains, shared B
    sconvm_k<<<1024, 256, 0, stream>>>(Fb0, idxmap, alist, cnt, wfs0a, cs0a, cb0a, Fb1);
    sconvm_k<<<1024, 256, 0, stream>>>(Fb1, idxmap, alist, cnt, wfs0b, cs0b, cb0b, Fb2);
    // down0 -> 64^3 x 32 bf16 NDHWC — M=32/wave, 4 acc chains, shared B
    convd0m_k<<<2048, 256, 0, stream>>>(Fb2, idxmap, fd0, csd0, cbd0, m1, Rb1);
    // 64^3 stage — M=32/wave, 2x2-row LDS-staged (512-thread blocks, 64 KB LDS)
    mconvw_k<64,32,32,1,false><<<1024, 512, 0, stream>>>(Rb1, f1a, cs1a, cb1a, m1, Rb2, flag);
    mconvw_k<64,32,32,1,false><<<1024, 512, 0, stream>>>(Rb2, f1b, cs1b, cb1b, m1, Rb1, flag);
    // down1 -> 32^3 x 64 (stride 2, NSPLIT=2)
    mconv_k<64,32,32,64,2,2,false><<<1024, 256, 0, stream>>>(Rb1, fd1, csd1, cbd1, m2, Rb2, flag);
    // 32^3 stage — CSPLIT=2
    mconvw_k<32,64,64,2,false><<<256, 512, 0, stream>>>(Rb2, f2a, cs2a, cb2a, m2, Rb1, flag);
    mconvw_k<32,64,64,2,false><<<256, 512, 0, stream>>>(Rb1, f2b, cs2b, cb2b, m2, Rb2, flag);
    // final conv: NCDHW f32 (or bf16 per flag) to d_out
    mconvw_k<32,64,64,2,true ><<<256, 512, 0, stream>>>(Rb2, f2c, cs2c, cb2c, m2, d_out, flag);
}